// Round 7
// baseline (947.908 us; speedup 1.0000x reference)
//
#include <hip/hip_runtime.h>
#include <math.h>

// ---------------------------------------------------------------------------
// MultiGraphClassifier on MI355X.
// Pipeline: 2x GraphConv per graph + cross-graph fusion + tiny head.
// Strategy: CSR build per call (XCD-sharded counting sort, atomic-free
// scatter), gather-side aggregation over bf16 tables, bf16-MFMA GEMMs with
// fp32 accumulate and fused degree-scale / bias / fusion-add epilogues.
// Note: softmax over a length-1 axis == 1.0, so emb = norm(a) + norm(f).
// R1: 3-phase scan. R3: atomic-free scatter via rank capture.
// R4: bf16 MFMA GEMMs + bf16 gather tables. R5: 4-wide agg unroll + fusion.
// R6: count2 was bound by device-scope atomic writeback (159MB WRITE_SIZE =
//     4.8M atomics x 64B at the memory-side coherence point). Shard the
//     histograms 8x by XCC_ID and use workgroup-scope atomics -> RMW executes
//     in the XCD-local L2 (legal: one XCD per shard; atomics always run at
//     TCC, never L1). combine pass folds shards -> isr + per-shard prefixes.
// ---------------------------------------------------------------------------

typedef __attribute__((ext_vector_type(8))) short bf16x8;
typedef __attribute__((ext_vector_type(4))) float f32x4;

#define XCC_GETREG_IMM 6164  // hwreg(id=20 XCC_ID, offset=0, size=4)

static __device__ inline unsigned short f2bf(float f) {
  unsigned u = __float_as_uint(f);
  unsigned r = (u + 0x7fff + ((u >> 16) & 1)) >> 16;  // RNE
  return (unsigned short)r;
}
static __device__ inline float bf2f(unsigned short h) {
  return __uint_as_float(((unsigned)h) << 16);
}

// Zero the tiny accumulators (sums + embeddings) in one 1-block dispatch.
__global__ void zero_small_kernel(float* __restrict__ s0, float* __restrict__ s1, int ns,
                                  float* __restrict__ ea, unsigned* __restrict__ ef, int ne) {
  int i = threadIdx.x;
  if (i < ns) { s0[i] = 0.f; s1[i] = 0.f; }
  if (i < ne) { ea[i] = 0.f; ef[i] = 0u; }
}

// XCD-sharded degree histograms + local-rank capture. Workgroup-scope
// atomics stay in the XCD-local L2 (shard index == own XCC -> correct).
__global__ void count2_kernel(const int* __restrict__ a_src, const int* __restrict__ a_dst,
                              int* __restrict__ co_sh_a, int* __restrict__ ci_sh_a,
                              int* __restrict__ rank_a, int e_a, int n_a,
                              const int* __restrict__ f_src, const int* __restrict__ f_dst,
                              int* __restrict__ co_sh_f, int* __restrict__ ci_sh_f,
                              int* __restrict__ rank_f, int e_f, int n_f) {
  int e = blockIdx.x * blockDim.x + threadIdx.x;
  int xcc = __builtin_amdgcn_s_getreg(XCC_GETREG_IMM) & 7;
  if (e < e_a) {
    __hip_atomic_fetch_add(&co_sh_a[xcc * n_a + a_src[e]], 1, __ATOMIC_RELAXED,
                           __HIP_MEMORY_SCOPE_WORKGROUP);
    int lr = __hip_atomic_fetch_add(&ci_sh_a[xcc * n_a + a_dst[e]], 1, __ATOMIC_RELAXED,
                                    __HIP_MEMORY_SCOPE_WORKGROUP);
    rank_a[e] = (xcc << 24) | lr;
  } else if (e - e_a < e_f) {
    int i = e - e_a;
    __hip_atomic_fetch_add(&co_sh_f[xcc * n_f + f_src[i]], 1, __ATOMIC_RELAXED,
                           __HIP_MEMORY_SCOPE_WORKGROUP);
    int lr = __hip_atomic_fetch_add(&ci_sh_f[xcc * n_f + f_dst[i]], 1, __ATOMIC_RELAXED,
                                    __HIP_MEMORY_SCOPE_WORKGROUP);
    rank_f[i] = (xcc << 24) | lr;
  }
}

// Fold shards: out-degree sum -> isr_out; in-degree shard counts -> in-place
// exclusive prefixes + total (cnt_in) -> isr_in. Both graphs per dispatch.
__global__ void combine_kernel(int* __restrict__ co_sh_a, int* __restrict__ ci_sh_a,
                               float* __restrict__ io_a, float* __restrict__ ii_a,
                               int* __restrict__ cnt_in_a, int n_a,
                               int* __restrict__ co_sh_f, int* __restrict__ ci_sh_f,
                               float* __restrict__ io_f, float* __restrict__ ii_f,
                               int* __restrict__ cnt_in_f, int n_f) {
  int i = blockIdx.x * blockDim.x + threadIdx.x;
  if (i < n_a) {
    int co = 0;
#pragma unroll
    for (int x = 0; x < 8; ++x) co += co_sh_a[x * n_a + i];
    io_a[i] = 1.0f / sqrtf((float)(co < 1 ? 1 : co));
    int run = 0;
#pragma unroll
    for (int x = 0; x < 8; ++x) {
      int v = ci_sh_a[x * n_a + i];
      ci_sh_a[x * n_a + i] = run;
      run += v;
    }
    cnt_in_a[i] = run;
    ii_a[i] = 1.0f / sqrtf((float)(run < 1 ? 1 : run));
  }
  if (i < n_f) {
    int co = 0;
#pragma unroll
    for (int x = 0; x < 8; ++x) co += co_sh_f[x * n_f + i];
    io_f[i] = 1.0f / sqrtf((float)(co < 1 ? 1 : co));
    int run = 0;
#pragma unroll
    for (int x = 0; x < 8; ++x) {
      int v = ci_sh_f[x * n_f + i];
      ci_sh_f[x * n_f + i] = run;
      run += v;
    }
    cnt_in_f[i] = run;
    ii_f[i] = 1.0f / sqrtf((float)(run < 1 ? 1 : run));
  }
}

// ---- 3-phase exclusive scan, both graphs per dispatch; tile = 4096 ----
__global__ __launch_bounds__(256) void blocksum2_kernel(
    const int* __restrict__ cnt_a, int n_a, const int* __restrict__ cnt_f, int n_f,
    int* __restrict__ blksum, int Ba) {
  __shared__ int red[256];
  bool isA = (int)blockIdx.x < Ba;
  const int* cnt = isA ? cnt_a : cnt_f;
  int n = isA ? n_a : n_f;
  int b = isA ? blockIdx.x : blockIdx.x - Ba;
  int base = b * 4096 + threadIdx.x * 16;
  int s = 0;
#pragma unroll
  for (int j = 0; j < 16; ++j) {
    int idx = base + j;
    if (idx < n) s += cnt[idx];
  }
  red[threadIdx.x] = s;
  __syncthreads();
  for (int o = 128; o > 0; o >>= 1) {
    if (threadIdx.x < o) red[threadIdx.x] += red[threadIdx.x + o];
    __syncthreads();
  }
  if (threadIdx.x == 0) blksum[blockIdx.x] = red[0];
}

__global__ __launch_bounds__(64) void blkscan2_kernel(int* __restrict__ blksum, int Ba, int Bf) {
  int t = threadIdx.x;
#pragma unroll
  for (int seg = 0; seg < 2; ++seg) {
    int off = seg ? Ba : 0;
    int B = seg ? Bf : Ba;
    int v = (t < B) ? blksum[off + t] : 0;
    int inc = v;
#pragma unroll
    for (int o = 1; o < 64; o <<= 1) {
      int u = __shfl_up(inc, o, 64);
      if (t >= o) inc += u;
    }
    if (t < B) blksum[off + t] = inc - v;  // exclusive
  }
}

__global__ __launch_bounds__(256) void offsets2_kernel(
    const int* __restrict__ cnt_a, int* __restrict__ offs_a, int n_a,
    const int* __restrict__ cnt_f, int* __restrict__ offs_f, int n_f,
    const int* __restrict__ blkoffs, int Ba) {
  __shared__ int part[256];
  bool isA = (int)blockIdx.x < Ba;
  const int* cnt = isA ? cnt_a : cnt_f;
  int* offs = isA ? offs_a : offs_f;
  int n = isA ? n_a : n_f;
  int b = isA ? blockIdx.x : blockIdx.x - Ba;
  int base = b * 4096 + threadIdx.x * 16;
  int c[16];
  int s = 0;
#pragma unroll
  for (int j = 0; j < 16; ++j) {
    int idx = base + j;
    c[j] = (idx < n) ? cnt[idx] : 0;
    s += c[j];
  }
  part[threadIdx.x] = s;
  __syncthreads();
  for (int o = 1; o < 256; o <<= 1) {
    int v = (threadIdx.x >= o) ? part[threadIdx.x - o] : 0;
    __syncthreads();
    part[threadIdx.x] += v;
    __syncthreads();
  }
  int run = blkoffs[blockIdx.x] + part[threadIdx.x] - s;
#pragma unroll
  for (int j = 0; j < 16; ++j) {
    int idx = base + j;
    if (idx < n) {
      offs[idx] = run;
      run += c[j];
      if (idx == n - 1) offs[n] = run;
    }
  }
}

// Atomic-free scatter: slot = offs[dst] + shard_prefix[xcc][dst] + local_rank.
__global__ void scatter2_kernel(const int* __restrict__ a_src, const int* __restrict__ a_dst,
                                const int* __restrict__ offs_a, const int* __restrict__ rank_a,
                                const int* __restrict__ ci_sh_a, int* __restrict__ csr_a,
                                int e_a, int n_a,
                                const int* __restrict__ f_src, const int* __restrict__ f_dst,
                                const int* __restrict__ offs_f, const int* __restrict__ rank_f,
                                const int* __restrict__ ci_sh_f, int* __restrict__ csr_f,
                                int e_f, int n_f) {
  int e = blockIdx.x * blockDim.x + threadIdx.x;
  if (e < e_a) {
    int d = a_dst[e];
    int rp = rank_a[e];
    csr_a[offs_a[d] + ci_sh_a[(rp >> 24) * n_a + d] + (rp & 0xFFFFFF)] = a_src[e];
  } else if (e - e_a < e_f) {
    int i = e - e_a;
    int d = f_dst[i];
    int rp = rank_f[i];
    csr_f[offs_f[d] + ci_sh_f[(rp >> 24) * n_f + d] + (rp & 0xFFFFFF)] = f_src[i];
  }
}

// ---------------------------------------------------------------------------
// bf16-MFMA GEMM: C[M,N] = epi( (A[M,K](+s*add_vec[K])) @ B[K,N] )
// fp32 global inputs cast bf16 in LDS staging; fp32 MFMA accumulate.
// epi: *rowscale[M]?  +bias[N]?  out bf16 or fp32. N%64==0, K%64==0.
// ---------------------------------------------------------------------------
#define LDT 72
__global__ __launch_bounds__(256) void gemm_mfma_kernel(
    const float* __restrict__ A, const float* __restrict__ B, void* __restrict__ C,
    int M, int N, int K,
    const float* __restrict__ add_vec, float add_scale,
    const float* __restrict__ rowscale, const float* __restrict__ bias, int out_bf16) {
  __shared__ __align__(16) short As[64 * LDT];  // [m][k]
  __shared__ __align__(16) short Bs[64 * LDT];  // [n][k] (transposed)
  const int m0 = blockIdx.x * 64, n0 = blockIdx.y * 64;
  const int tid = threadIdx.x;
  const int lane = tid & 63, w = tid >> 6;
  const int q = lane >> 4, l16 = lane & 15;
  const int srow = tid >> 2, schunk = (tid & 3) * 16;
  f32x4 acc[4] = {};
  for (int k0 = 0; k0 < K; k0 += 64) {
    {
      int m = m0 + srow;
      float tmp[16];
      if (m < M) {
        const float* s = A + (size_t)m * K + k0 + schunk;
#pragma unroll
        for (int i = 0; i < 16; i += 4) {
          float4 v = *reinterpret_cast<const float4*>(s + i);
          tmp[i] = v.x; tmp[i + 1] = v.y; tmp[i + 2] = v.z; tmp[i + 3] = v.w;
        }
        if (add_vec) {
#pragma unroll
          for (int i = 0; i < 16; ++i) tmp[i] += add_scale * add_vec[k0 + schunk + i];
        }
      } else {
#pragma unroll
        for (int i = 0; i < 16; ++i) tmp[i] = 0.f;
      }
#pragma unroll
      for (int i = 0; i < 16; ++i) As[srow * LDT + schunk + i] = (short)f2bf(tmp[i]);
    }
    {
      const float* s = B + (size_t)(k0 + srow) * N + n0 + schunk;
#pragma unroll
      for (int i = 0; i < 16; i += 4) {
        float4 v = *reinterpret_cast<const float4*>(s + i);
        Bs[(schunk + i + 0) * LDT + srow] = (short)f2bf(v.x);
        Bs[(schunk + i + 1) * LDT + srow] = (short)f2bf(v.y);
        Bs[(schunk + i + 2) * LDT + srow] = (short)f2bf(v.z);
        Bs[(schunk + i + 3) * LDT + srow] = (short)f2bf(v.w);
      }
    }
    __syncthreads();
#pragma unroll
    for (int kk = 0; kk < 2; ++kk) {
      bf16x8 af = *reinterpret_cast<const bf16x8*>(&As[(w * 16 + l16) * LDT + kk * 32 + q * 8]);
#pragma unroll
      for (int nt = 0; nt < 4; ++nt) {
        bf16x8 bf = *reinterpret_cast<const bf16x8*>(&Bs[(nt * 16 + l16) * LDT + kk * 32 + q * 8]);
        acc[nt] = __builtin_amdgcn_mfma_f32_16x16x32_bf16(af, bf, acc[nt], 0, 0, 0);
      }
    }
    __syncthreads();
  }
#pragma unroll
  for (int nt = 0; nt < 4; ++nt) {
    int gcol = n0 + nt * 16 + l16;
    float bv = bias ? bias[gcol] : 0.f;
#pragma unroll
    for (int r = 0; r < 4; ++r) {
      int grow = m0 + w * 16 + q * 4 + r;
      if (grow < M) {
        float v = acc[nt][r];
        if (rowscale) v *= rowscale[grow];
        v += bv;
        if (out_bf16)
          ((unsigned short*)C)[(size_t)grow * N + gcol] = f2bf(v);
        else
          ((float*)C)[(size_t)grow * N + gcol] = v;
      }
    }
  }
}

// H[node] = relu( (sum_{e in CSR[node]} XW_bf16[src(e)]) * isr_in[node] + b )
// 32 threads per node, 8 nodes/block, 4-wide unroll (4 row loads in flight).
__global__ __launch_bounds__(256) void agg_kernel(
    const unsigned short* __restrict__ XW, const int* __restrict__ offs,
    const int* __restrict__ csr, const float* __restrict__ isr_in,
    const float* __restrict__ bias, float* __restrict__ H, int n) {
  int lane = threadIdx.x & 31;
  int node = blockIdx.x * 8 + (threadIdx.x >> 5);
  if (node >= n) return;
  int e0 = offs[node], e1 = offs[node + 1];
  float4 a0 = make_float4(0.f, 0.f, 0.f, 0.f);
  float4 a1 = a0, a2 = a0, a3 = a0;
  int e = e0;
  for (; e + 4 <= e1; e += 4) {
    int s0 = csr[e], s1 = csr[e + 1], s2 = csr[e + 2], s3 = csr[e + 3];
    ushort4 v0 = *reinterpret_cast<const ushort4*>(&XW[(size_t)s0 * 128 + lane * 4]);
    ushort4 v1 = *reinterpret_cast<const ushort4*>(&XW[(size_t)s1 * 128 + lane * 4]);
    ushort4 v2 = *reinterpret_cast<const ushort4*>(&XW[(size_t)s2 * 128 + lane * 4]);
    ushort4 v3 = *reinterpret_cast<const ushort4*>(&XW[(size_t)s3 * 128 + lane * 4]);
    a0.x += bf2f(v0.x); a0.y += bf2f(v0.y); a0.z += bf2f(v0.z); a0.w += bf2f(v0.w);
    a1.x += bf2f(v1.x); a1.y += bf2f(v1.y); a1.z += bf2f(v1.z); a1.w += bf2f(v1.w);
    a2.x += bf2f(v2.x); a2.y += bf2f(v2.y); a2.z += bf2f(v2.z); a2.w += bf2f(v2.w);
    a3.x += bf2f(v3.x); a3.y += bf2f(v3.y); a3.z += bf2f(v3.z); a3.w += bf2f(v3.w);
  }
  for (; e < e1; ++e) {
    int s = csr[e];
    ushort4 v = *reinterpret_cast<const ushort4*>(&XW[(size_t)s * 128 + lane * 4]);
    a0.x += bf2f(v.x); a0.y += bf2f(v.y); a0.z += bf2f(v.z); a0.w += bf2f(v.w);
  }
  float4 acc;
  acc.x = (a0.x + a1.x) + (a2.x + a3.x);
  acc.y = (a0.y + a1.y) + (a2.y + a3.y);
  acc.z = (a0.z + a1.z) + (a2.z + a3.z);
  acc.w = (a0.w + a1.w) + (a2.w + a3.w);
  float sc = isr_in[node];
  float4 b = *reinterpret_cast<const float4*>(&bias[lane * 4]);
  float4 o;
  o.x = fmaxf(fmaf(acc.x, sc, b.x), 0.f);
  o.y = fmaxf(fmaf(acc.y, sc, b.y), 0.f);
  o.z = fmaxf(fmaf(acc.z, sc, b.z), 0.f);
  o.w = fmaxf(fmaf(acc.w, sc, b.w), 0.f);
  *reinterpret_cast<float4*>(&H[(size_t)node * 128 + lane * 4]) = o;
}

// out[col] += column sums of X[n, ncol]; out pre-zeroed. ncol | 256.
__global__ __launch_bounds__(256) void colsum_kernel(const float* __restrict__ X,
                                                     float* __restrict__ out, int n, int ncol) {
  __shared__ float s[256];
  int col = threadIdx.x % ncol;
  int rpb = 256 / ncol;
  int rb = threadIdx.x / ncol;
  float acc = 0.f;
  for (int r = blockIdx.x * rpb + rb; r < n; r += gridDim.x * rpb)
    acc += X[(size_t)r * ncol + col];
  s[threadIdx.x] = acc;
  __syncthreads();
  if (threadIdx.x < ncol) {
    float v = 0.f;
    for (int i = 0; i < rpb; ++i) v += s[threadIdx.x + i * ncol];
    atomicAdd(&out[col], v);  // device scope: cross-XCD reduction
  }
}

// out[col] = max over rows (X >= 0 relu output; out pre-zeroed).
__global__ __launch_bounds__(256) void colmax_kernel(const float* __restrict__ X,
                                                     unsigned* __restrict__ out, int n, int ncol) {
  __shared__ float s[256];
  int col = threadIdx.x % ncol;
  int rpb = 256 / ncol;
  int rb = threadIdx.x / ncol;
  float acc = 0.f;
  for (int r = blockIdx.x * rpb + rb; r < n; r += gridDim.x * rpb)
    acc = fmaxf(acc, X[(size_t)r * ncol + col]);
  s[threadIdx.x] = acc;
  __syncthreads();
  if (threadIdx.x < ncol) {
    float v = s[threadIdx.x];
    for (int i = 1; i < rpb; ++i) v = fmaxf(v, s[threadIdx.x + i * ncol]);
    atomicMax(&out[col], __float_as_uint(v));  // device scope
  }
}

// norm_embed(a) + norm_embed(f) then @ W_cls + b_cls. Single block of 128.
__global__ __launch_bounds__(128) void final_kernel(
    const float* __restrict__ emb_a_sum, const unsigned* __restrict__ emb_f_bits,
    const float* __restrict__ W_cls, const float* __restrict__ b_cls,
    float* __restrict__ out, float inv_n_apig, int ncls) {
  __shared__ float red[128];
  __shared__ float emb[128];
  int t = threadIdx.x;
  float a = emb_a_sum[t] * inv_n_apig;
  float f = __uint_as_float(emb_f_bits[t]);

  float vals[2] = {a, f};
  float norms[2];
#pragma unroll
  for (int which = 0; which < 2; ++which) {
    float x = vals[which];
    red[t] = x;
    __syncthreads();
    for (int o = 64; o > 0; o >>= 1) {
      if (t < o) red[t] += red[t + o];
      __syncthreads();
    }
    float mean = red[0] / 128.f;
    __syncthreads();
    float d = x - mean;
    red[t] = d * d;
    __syncthreads();
    for (int o = 64; o > 0; o >>= 1) {
      if (t < o) red[t] += red[t + o];
      __syncthreads();
    }
    float stdv = sqrtf(red[0] / 127.f);  // ddof=1
    __syncthreads();
    float z = d / stdv;
    red[t] = z;
    __syncthreads();
    for (int o = 64; o > 0; o >>= 1) {
      if (t < o) red[t] = fminf(red[t], red[t + o]);
      __syncthreads();
    }
    float zmin = red[0];
    __syncthreads();
    red[t] = z;
    __syncthreads();
    for (int o = 64; o > 0; o >>= 1) {
      if (t < o) red[t] = fmaxf(red[t], red[t + o]);
      __syncthreads();
    }
    float zmax = red[0];
    __syncthreads();
    norms[which] = (z - zmin) / (zmax - zmin);
  }

  emb[t] = norms[0] + norms[1];
  __syncthreads();
  if (t < ncls) {
    float acc = b_cls[t];
    for (int k = 0; k < 128; ++k) acc = fmaf(emb[k], W_cls[k * ncls + t], acc);
    out[t] = acc;
  }
}

extern "C" void kernel_launch(void* const* d_in, const int* in_sizes, int n_in,
                              void* d_out, int out_size, void* d_ws, size_t ws_size,
                              hipStream_t stream) {
  const float* apig_feat = (const float*)d_in[0];
  const float* fcg_feat = (const float*)d_in[1];
  const float* W_a1 = (const float*)d_in[2];
  const float* b_a1 = (const float*)d_in[3];
  const float* W_a2 = (const float*)d_in[4];
  const float* b_a2 = (const float*)d_in[5];
  const float* W_f1 = (const float*)d_in[6];
  const float* b_f1 = (const float*)d_in[7];
  const float* W_f2 = (const float*)d_in[8];
  const float* b_f2 = (const float*)d_in[9];
  const float* W1 = (const float*)d_in[10];
  const float* b1 = (const float*)d_in[11];
  const float* W2 = (const float*)d_in[12];
  const float* b2 = (const float*)d_in[13];
  // d_in[14]/d_in[15] (W_attn, b_attn): dead — softmax over length-1 axis == 1.
  const float* W_cls = (const float*)d_in[16];
  const float* b_cls = (const float*)d_in[17];
  const int* a_src = (const int*)d_in[18];
  const int* a_dst = (const int*)d_in[19];
  const int* f_src = (const int*)d_in[20];
  const int* f_dst = (const int*)d_in[21];

  const int hidden = in_sizes[3];             // 128
  const int united = in_sizes[11];            // 64
  const int ncls = in_sizes[17];              // 10
  const int apig_dim = in_sizes[2] / hidden;  // 256
  const int fcg_dim = in_sizes[6] / hidden;   // 128
  const int n_a = in_sizes[0] / apig_dim;     // 50000
  const int n_f = in_sizes[1] / fcg_dim;      // 100000
  const int e_a = in_sizes[18];               // 800000
  const int e_f = in_sizes[20];               // 1600000

  // ---- workspace carve-up (all 256B aligned) ----
  char* w = (char*)d_ws;
  auto alloc = [&](size_t bytes) -> void* {
    void* p = (void*)w;
    w += (bytes + 255) & ~(size_t)255;
    return p;
  };
  float* isr_out_a = (float*)alloc((size_t)n_a * 4);
  float* isr_in_a = (float*)alloc((size_t)n_a * 4);
  float* isr_out_f = (float*)alloc((size_t)n_f * 4);
  float* isr_in_f = (float*)alloc((size_t)n_f * 4);
  // XCD shards: co_sh_a[8][n_a], ci_sh_a[8][n_a], co_sh_f[8][n_f], ci_sh_f[8][n_f]
  int* shards = (int*)alloc(((size_t)16 * n_a + (size_t)16 * n_f) * 4);
  int* co_sh_a = shards;
  int* ci_sh_a = shards + (size_t)8 * n_a;
  int* co_sh_f = shards + (size_t)16 * n_a;
  int* ci_sh_f = shards + (size_t)16 * n_a + (size_t)8 * n_f;
  int* cnt_in_a = (int*)alloc((size_t)n_a * 4);
  int* cnt_in_f = (int*)alloc((size_t)n_f * 4);
  int* offs_a = (int*)alloc((size_t)(n_a + 1) * 4);
  int* offs_f = (int*)alloc((size_t)(n_f + 1) * 4);
  int* rank_a = (int*)alloc((size_t)e_a * 4);
  int* rank_f = (int*)alloc((size_t)e_f * 4);
  int* csr_a = (int*)alloc((size_t)(e_a + 256) * 4);  // +guard
  int* csr_f = (int*)alloc((size_t)(e_f + 256) * 4);  // +guard
  int* blksum = (int*)alloc((size_t)128 * 4);
  unsigned short* G_a = (unsigned short*)alloc((size_t)n_a * hidden * 2);  // bf16 table
  float* H_a = (float*)alloc((size_t)n_a * hidden * 4);                    // h1 / a_dec / h2
  unsigned short* G_f = (unsigned short*)alloc((size_t)n_f * hidden * 2);
  float* H_f = (float*)alloc((size_t)n_f * hidden * 4);
  float* E_a = (float*)G_a;  // enc raw aliases G_a (disjoint lifetimes, same bytes)
  float* E_f = (float*)G_f;
  float* a_sum = (float*)alloc((size_t)united * 4);
  float* f_sum = (float*)alloc((size_t)united * 4);
  float* emb_a = (float*)alloc((size_t)hidden * 4);
  unsigned* emb_f = (unsigned*)alloc((size_t)hidden * 4);
  (void)ws_size;
  (void)n_in;
  (void)out_size;

  const int Ba = (n_a + 4095) / 4096;
  const int Bf = (n_f + 4095) / 4096;
  const int E_tot = e_a + e_f;

  dim3 blk(256);

  // ---- zero shard histograms (one memset) + tiny accumulators ----
  hipMemsetAsync(shards, 0, ((size_t)16 * n_a + (size_t)16 * n_f) * 4, stream);
  zero_small_kernel<<<1, 128, 0, stream>>>(a_sum, f_sum, united, emb_a, emb_f, hidden);

  // ---- degrees + rank + CSR (both graphs per dispatch) ----
  count2_kernel<<<(E_tot + 255) / 256, blk, 0, stream>>>(
      a_src, a_dst, co_sh_a, ci_sh_a, rank_a, e_a, n_a,
      f_src, f_dst, co_sh_f, ci_sh_f, rank_f, e_f, n_f);
  combine_kernel<<<(n_f + 255) / 256, blk, 0, stream>>>(
      co_sh_a, ci_sh_a, isr_out_a, isr_in_a, cnt_in_a, n_a,
      co_sh_f, ci_sh_f, isr_out_f, isr_in_f, cnt_in_f, n_f);
  blocksum2_kernel<<<Ba + Bf, blk, 0, stream>>>(cnt_in_a, n_a, cnt_in_f, n_f, blksum, Ba);
  blkscan2_kernel<<<1, 64, 0, stream>>>(blksum, Ba, Bf);
  offsets2_kernel<<<Ba + Bf, blk, 0, stream>>>(cnt_in_a, offs_a, n_a, cnt_in_f, offs_f, n_f,
                                               blksum, Ba);
  scatter2_kernel<<<(E_tot + 255) / 256, blk, 0, stream>>>(
      a_src, a_dst, offs_a, rank_a, ci_sh_a, csr_a, e_a, n_a,
      f_src, f_dst, offs_f, rank_f, ci_sh_f, csr_f, e_f, n_f);

  const int ga = (n_a + 63) / 64, gf = (n_f + 63) / 64;

  // ---- apig conv1 + enc ----
  gemm_mfma_kernel<<<dim3(ga, hidden / 64), blk, 0, stream>>>(
      apig_feat, W_a1, G_a, n_a, hidden, apig_dim, nullptr, 0.f, isr_out_a, nullptr, 1);
  agg_kernel<<<(n_a + 7) / 8, blk, 0, stream>>>(G_a, offs_a, csr_a, isr_in_a, b_a1, H_a, n_a);
  gemm_mfma_kernel<<<dim3(ga, united / 64), blk, 0, stream>>>(
      H_a, W1, E_a, n_a, united, hidden, nullptr, 0.f, nullptr, b1, 0);  // E_a=G_a (G_a dead)
  colsum_kernel<<<256, blk, 0, stream>>>(E_a, a_sum, n_a, united);

  // ---- fcg conv1 + enc ----
  gemm_mfma_kernel<<<dim3(gf, hidden / 64), blk, 0, stream>>>(
      fcg_feat, W_f1, G_f, n_f, hidden, fcg_dim, nullptr, 0.f, isr_out_f, nullptr, 1);
  agg_kernel<<<(n_f + 7) / 8, blk, 0, stream>>>(G_f, offs_f, csr_f, isr_in_f, b_f1, H_f, n_f);
  gemm_mfma_kernel<<<dim3(gf, united / 64), blk, 0, stream>>>(
      H_f, W1, E_f, n_f, united, hidden, nullptr, 0.f, nullptr, b1, 0);
  colsum_kernel<<<256, blk, 0, stream>>>(E_f, f_sum, n_f, united);

  // ---- apig dec + conv2 + mean ----
  gemm_mfma_kernel<<<dim3(ga, hidden / 64), blk, 0, stream>>>(
      E_a, W2, H_a, n_a, hidden, united, f_sum, 0.1f, nullptr, b2, 0);  // a_dec
  gemm_mfma_kernel<<<dim3(ga, hidden / 64), blk, 0, stream>>>(
      H_a, W_a2, G_a, n_a, hidden, hidden, nullptr, 0.f, isr_out_a, nullptr, 1);  // E_a dead
  agg_kernel<<<(n_a + 7) / 8, blk, 0, stream>>>(G_a, offs_a, csr_a, isr_in_a, b_a2, H_a, n_a);
  colsum_kernel<<<256, blk, 0, stream>>>(H_a, emb_a, n_a, hidden);

  // ---- fcg dec + conv2 + max ----
  gemm_mfma_kernel<<<dim3(gf, hidden / 64), blk, 0, stream>>>(
      E_f, W2, H_f, n_f, hidden, united, a_sum, 0.1f, nullptr, b2, 0);  // f_dec
  gemm_mfma_kernel<<<dim3(gf, hidden / 64), blk, 0, stream>>>(
      H_f, W_f2, G_f, n_f, hidden, hidden, nullptr, 0.f, isr_out_f, nullptr, 1);
  agg_kernel<<<(n_f + 7) / 8, blk, 0, stream>>>(G_f, offs_f, csr_f, isr_in_f, b_f2, H_f, n_f);
  colmax_kernel<<<256, blk, 0, stream>>>(H_f, emb_f, n_f, hidden);

  // ---- head ----
  final_kernel<<<1, 128, 0, stream>>>(emb_a, emb_f, W_cls, b_cls, (float*)d_out,
                                      1.0f / (float)n_a, ncls);
}

// Round 8
// 933.425 us; speedup vs baseline: 1.0155x; 1.0155x over previous
//
#include <hip/hip_runtime.h>
#include <math.h>

// ---------------------------------------------------------------------------
// MultiGraphClassifier on MI355X.
// Pipeline: 2x GraphConv per graph + cross-graph fusion + tiny head.
// Strategy: ATOMIC-FREE CSR build via MSD radix bucketing (high 9 bits) +
// per-bucket LDS counting sort (low 9 bits); offs emitted directly from the
// bucket scans. Gather-side aggregation over bf16 tables; bf16-MFMA GEMMs
// with fp32 accumulate and fused epilogues.
// Note: softmax over a length-1 axis == 1.0, so emb = norm(a) + norm(f).
// R1: 3-phase scan. R3: atomic-free scatter. R4: bf16 MFMA + bf16 tables.
// R5: 4-wide agg unroll + dispatch fusion.
// R6/R7: FALSIFIED: atomic scope/sharding changes nothing — every global
//   atomic RMW costs a fixed memory-side transaction (~21 G/s ceiling,
//   WRITE_SIZE identical across scope/sharding). Hence R8: zero global
//   atomics in the CSR build — radix machinery uses only LDS atomics.
// ---------------------------------------------------------------------------

typedef __attribute__((ext_vector_type(8))) short bf16x8;
typedef __attribute__((ext_vector_type(4))) float f32x4;

#define SORT_T 16384  // edges per phase-1 block

static __device__ inline unsigned short f2bf(float f) {
  unsigned u = __float_as_uint(f);
  unsigned r = (u + 0x7fff + ((u >> 16) & 1)) >> 16;  // RNE
  return (unsigned short)r;
}
static __device__ inline float bf2f(unsigned short h) {
  return __uint_as_float(((unsigned)h) << 16);
}

// Zero tiny accumulators + write offs sentinels. One block of 128.
__global__ void zero_small_kernel(float* __restrict__ s0, float* __restrict__ s1, int ns,
                                  float* __restrict__ ea, unsigned* __restrict__ ef, int ne,
                                  int* __restrict__ offs_a, int* __restrict__ offs_src_a,
                                  int n_a, int e_a,
                                  int* __restrict__ offs_f, int* __restrict__ offs_src_f,
                                  int n_f, int e_f) {
  int i = threadIdx.x;
  if (i < ns) { s0[i] = 0.f; s1[i] = 0.f; }
  if (i < ne) { ea[i] = 0.f; ef[i] = 0u; }
  if (i == 0) {
    offs_a[n_a] = e_a;
    offs_src_a[n_a] = e_a;
    offs_f[n_f] = e_f;
    offs_src_f[n_f] = e_f;
  }
}

// Combined key at edge i: apig -> key, fcg -> key + 65536 (18-bit space).
static __device__ inline int edge_key(const int* __restrict__ a_key,
                                      const int* __restrict__ f_key, int e_a, int i) {
  return (i < e_a) ? a_key[i] : (f_key[i - e_a] + 65536);
}

// Phase-1 histogram over high 9 bits. LDS atomics only.
__global__ __launch_bounds__(256) void radix_hist_kernel(
    const int* __restrict__ a_key, const int* __restrict__ f_key, int e_a, int E,
    int* __restrict__ blkhist, int B) {
  __shared__ int h[512];
  for (int i = threadIdx.x; i < 512; i += 256) h[i] = 0;
  __syncthreads();
  int base = blockIdx.x * SORT_T;
  int end = base + SORT_T;
  if (end > E) end = E;
  for (int i = base + threadIdx.x; i < end; i += 256)
    atomicAdd(&h[edge_key(a_key, f_key, e_a, i) >> 9], 1);
  __syncthreads();
  for (int i = threadIdx.x; i < 512; i += 256) blkhist[i * B + blockIdx.x] = h[i];
}

// Phase-1 scatter: each block derives its 512 global cursors from blkhist
// (redundant per-block reduction of the L2-hot 512xB table — no scan
// dispatch), then scatters keys (+payload) with LDS cursor bumps.
// Block 0 also stores the global bucket starts.
__global__ __launch_bounds__(256) void radix_scatter_kernel(
    const int* __restrict__ a_key, const int* __restrict__ f_key,
    const int* __restrict__ a_pay, const int* __restrict__ f_pay,  // null for key-only
    int e_a, int E, const int* __restrict__ blkhist, int B,
    int* __restrict__ okey, int* __restrict__ opay, int* __restrict__ binstart) {
  __shared__ int cur[512], tot[512], scanv[512];
  int b = blockIdx.x;
  for (int bin = threadIdx.x; bin < 512; bin += 256) {
    const int* row = blkhist + bin * B;
    int wb = 0, t = 0;
    for (int j = 0; j < B; ++j) {
      int v = row[j];
      t += v;
      wb += (j < b) ? v : 0;
    }
    cur[bin] = wb;
    tot[bin] = t;
    scanv[bin] = t;
  }
  __syncthreads();
  for (int o = 1; o < 512; o <<= 1) {
    int i0 = threadIdx.x, i1 = threadIdx.x + 256;
    int v0 = (i0 >= o) ? scanv[i0 - o] : 0;
    int v1 = (i1 >= o) ? scanv[i1 - o] : 0;
    __syncthreads();
    scanv[i0] += v0;
    scanv[i1] += v1;
    __syncthreads();
  }
  for (int bin = threadIdx.x; bin < 512; bin += 256) {
    int start = scanv[bin] - tot[bin];  // exclusive
    cur[bin] += start;
    if (b == 0) binstart[bin] = start;
  }
  __syncthreads();
  int base = b * SORT_T;
  int end = base + SORT_T;
  if (end > E) end = E;
  for (int i = base + threadIdx.x; i < end; i += 256) {
    int k = edge_key(a_key, f_key, e_a, i);
    int pos = atomicAdd(&cur[k >> 9], 1);
    okey[pos] = k;
    if (opay) opay[pos] = (i < e_a) ? a_pay[i] : f_pay[i - e_a];
  }
}

// Phase-2 (dst): per-bucket LDS counting sort over low 9 bits. Writes csr
// (payload) at final positions and offs for the bucket's 512 node keys.
__global__ __launch_bounds__(256) void bucket_dst_kernel(
    const int* __restrict__ k1, const int* __restrict__ p1,
    const int* __restrict__ binstart, int E, int e_a,
    int* __restrict__ csr, int* __restrict__ offs_a, int n_a,
    int* __restrict__ offs_f, int n_f) {
  __shared__ int h[512], x[512], cur[512];
  int b = blockIdx.x;
  int s = binstart[b];
  int e = (b == 511) ? E : binstart[b + 1];
  for (int i = threadIdx.x; i < 512; i += 256) h[i] = 0;
  __syncthreads();
  for (int i = s + threadIdx.x; i < e; i += 256) atomicAdd(&h[k1[i] & 511], 1);
  __syncthreads();
  for (int i = threadIdx.x; i < 512; i += 256) x[i] = h[i];
  __syncthreads();
  for (int o = 1; o < 512; o <<= 1) {
    int i0 = threadIdx.x, i1 = threadIdx.x + 256;
    int v0 = (i0 >= o) ? x[i0 - o] : 0;
    int v1 = (i1 >= o) ? x[i1 - o] : 0;
    __syncthreads();
    x[i0] += v0;
    x[i1] += v1;
    __syncthreads();
  }
  for (int low = threadIdx.x; low < 512; low += 256) {
    int gpos = s + x[low] - h[low];  // exclusive start of this key's run
    cur[low] = gpos;
    int key = (b << 9) | low;
    if (key < 65536) {
      if (key < n_a) offs_a[key] = gpos;
    } else {
      int v = key - 65536;
      if (v < n_f) offs_f[v] = gpos - e_a;
    }
  }
  __syncthreads();
  for (int i = s + threadIdx.x; i < e; i += 256) {
    int pos = atomicAdd(&cur[k1[i] & 511], 1);
    csr[pos] = p1[i];
  }
}

// Phase-2 (src): histogram + scan only -> offs_src (out-degree boundaries).
__global__ __launch_bounds__(256) void bucket_src_kernel(
    const int* __restrict__ k1, const int* __restrict__ binstart, int E, int e_a,
    int* __restrict__ offs_src_a, int n_a, int* __restrict__ offs_src_f, int n_f) {
  __shared__ int h[512], x[512];
  int b = blockIdx.x;
  int s = binstart[b];
  int e = (b == 511) ? E : binstart[b + 1];
  for (int i = threadIdx.x; i < 512; i += 256) h[i] = 0;
  __syncthreads();
  for (int i = s + threadIdx.x; i < e; i += 256) atomicAdd(&h[k1[i] & 511], 1);
  __syncthreads();
  for (int i = threadIdx.x; i < 512; i += 256) x[i] = h[i];
  __syncthreads();
  for (int o = 1; o < 512; o <<= 1) {
    int i0 = threadIdx.x, i1 = threadIdx.x + 256;
    int v0 = (i0 >= o) ? x[i0 - o] : 0;
    int v1 = (i1 >= o) ? x[i1 - o] : 0;
    __syncthreads();
    x[i0] += v0;
    x[i1] += v1;
    __syncthreads();
  }
  for (int low = threadIdx.x; low < 512; low += 256) {
    int gpos = s + x[low] - h[low];
    int key = (b << 9) | low;
    if (key < 65536) {
      if (key < n_a) offs_src_a[key] = gpos;
    } else {
      int v = key - 65536;
      if (v < n_f) offs_src_f[v] = gpos - e_a;
    }
  }
}

// isr from offs diffs (needs sentinels).
__global__ void isr_kernel(const int* __restrict__ offs_a, const int* __restrict__ offs_src_a,
                           float* __restrict__ io_a, float* __restrict__ ii_a, int n_a,
                           const int* __restrict__ offs_f, const int* __restrict__ offs_src_f,
                           float* __restrict__ io_f, float* __restrict__ ii_f, int n_f) {
  int i = blockIdx.x * blockDim.x + threadIdx.x;
  if (i < n_a) {
    int ci = offs_a[i + 1] - offs_a[i];
    int co = offs_src_a[i + 1] - offs_src_a[i];
    ii_a[i] = 1.0f / sqrtf((float)(ci < 1 ? 1 : ci));
    io_a[i] = 1.0f / sqrtf((float)(co < 1 ? 1 : co));
  }
  if (i < n_f) {
    int ci = offs_f[i + 1] - offs_f[i];
    int co = offs_src_f[i + 1] - offs_src_f[i];
    ii_f[i] = 1.0f / sqrtf((float)(ci < 1 ? 1 : ci));
    io_f[i] = 1.0f / sqrtf((float)(co < 1 ? 1 : co));
  }
}

// ---------------------------------------------------------------------------
// bf16-MFMA GEMM: C[M,N] = epi( (A[M,K](+s*add_vec[K])) @ B[K,N] )
// fp32 global inputs cast bf16 in LDS staging; fp32 MFMA accumulate.
// epi: *rowscale[M]?  +bias[N]?  out bf16 or fp32. N%64==0, K%64==0.
// ---------------------------------------------------------------------------
#define LDT 72
__global__ __launch_bounds__(256) void gemm_mfma_kernel(
    const float* __restrict__ A, const float* __restrict__ B, void* __restrict__ C,
    int M, int N, int K,
    const float* __restrict__ add_vec, float add_scale,
    const float* __restrict__ rowscale, const float* __restrict__ bias, int out_bf16) {
  __shared__ __align__(16) short As[64 * LDT];  // [m][k]
  __shared__ __align__(16) short Bs[64 * LDT];  // [n][k] (transposed)
  const int m0 = blockIdx.x * 64, n0 = blockIdx.y * 64;
  const int tid = threadIdx.x;
  const int lane = tid & 63, w = tid >> 6;
  const int q = lane >> 4, l16 = lane & 15;
  const int srow = tid >> 2, schunk = (tid & 3) * 16;
  f32x4 acc[4] = {};
  for (int k0 = 0; k0 < K; k0 += 64) {
    {
      int m = m0 + srow;
      float tmp[16];
      if (m < M) {
        const float* s = A + (size_t)m * K + k0 + schunk;
#pragma unroll
        for (int i = 0; i < 16; i += 4) {
          float4 v = *reinterpret_cast<const float4*>(s + i);
          tmp[i] = v.x; tmp[i + 1] = v.y; tmp[i + 2] = v.z; tmp[i + 3] = v.w;
        }
        if (add_vec) {
#pragma unroll
          for (int i = 0; i < 16; ++i) tmp[i] += add_scale * add_vec[k0 + schunk + i];
        }
      } else {
#pragma unroll
        for (int i = 0; i < 16; ++i) tmp[i] = 0.f;
      }
#pragma unroll
      for (int i = 0; i < 16; ++i) As[srow * LDT + schunk + i] = (short)f2bf(tmp[i]);
    }
    {
      const float* s = B + (size_t)(k0 + srow) * N + n0 + schunk;
#pragma unroll
      for (int i = 0; i < 16; i += 4) {
        float4 v = *reinterpret_cast<const float4*>(s + i);
        Bs[(schunk + i + 0) * LDT + srow] = (short)f2bf(v.x);
        Bs[(schunk + i + 1) * LDT + srow] = (short)f2bf(v.y);
        Bs[(schunk + i + 2) * LDT + srow] = (short)f2bf(v.z);
        Bs[(schunk + i + 3) * LDT + srow] = (short)f2bf(v.w);
      }
    }
    __syncthreads();
#pragma unroll
    for (int kk = 0; kk < 2; ++kk) {
      bf16x8 af = *reinterpret_cast<const bf16x8*>(&As[(w * 16 + l16) * LDT + kk * 32 + q * 8]);
#pragma unroll
      for (int nt = 0; nt < 4; ++nt) {
        bf16x8 bf = *reinterpret_cast<const bf16x8*>(&Bs[(nt * 16 + l16) * LDT + kk * 32 + q * 8]);
        acc[nt] = __builtin_amdgcn_mfma_f32_16x16x32_bf16(af, bf, acc[nt], 0, 0, 0);
      }
    }
    __syncthreads();
  }
#pragma unroll
  for (int nt = 0; nt < 4; ++nt) {
    int gcol = n0 + nt * 16 + l16;
    float bv = bias ? bias[gcol] : 0.f;
#pragma unroll
    for (int r = 0; r < 4; ++r) {
      int grow = m0 + w * 16 + q * 4 + r;
      if (grow < M) {
        float v = acc[nt][r];
        if (rowscale) v *= rowscale[grow];
        v += bv;
        if (out_bf16)
          ((unsigned short*)C)[(size_t)grow * N + gcol] = f2bf(v);
        else
          ((float*)C)[(size_t)grow * N + gcol] = v;
      }
    }
  }
}

// H[node] = relu( (sum_{e in CSR[node]} XW_bf16[src(e)]) * isr_in[node] + b )
// 32 threads per node, 8 nodes/block, 4-wide unroll (4 row loads in flight).
__global__ __launch_bounds__(256) void agg_kernel(
    const unsigned short* __restrict__ XW, const int* __restrict__ offs,
    const int* __restrict__ csr, const float* __restrict__ isr_in,
    const float* __restrict__ bias, float* __restrict__ H, int n) {
  int lane = threadIdx.x & 31;
  int node = blockIdx.x * 8 + (threadIdx.x >> 5);
  if (node >= n) return;
  int e0 = offs[node], e1 = offs[node + 1];
  float4 a0 = make_float4(0.f, 0.f, 0.f, 0.f);
  float4 a1 = a0, a2 = a0, a3 = a0;
  int e = e0;
  for (; e + 4 <= e1; e += 4) {
    int s0 = csr[e], s1 = csr[e + 1], s2 = csr[e + 2], s3 = csr[e + 3];
    ushort4 v0 = *reinterpret_cast<const ushort4*>(&XW[(size_t)s0 * 128 + lane * 4]);
    ushort4 v1 = *reinterpret_cast<const ushort4*>(&XW[(size_t)s1 * 128 + lane * 4]);
    ushort4 v2 = *reinterpret_cast<const ushort4*>(&XW[(size_t)s2 * 128 + lane * 4]);
    ushort4 v3 = *reinterpret_cast<const ushort4*>(&XW[(size_t)s3 * 128 + lane * 4]);
    a0.x += bf2f(v0.x); a0.y += bf2f(v0.y); a0.z += bf2f(v0.z); a0.w += bf2f(v0.w);
    a1.x += bf2f(v1.x); a1.y += bf2f(v1.y); a1.z += bf2f(v1.z); a1.w += bf2f(v1.w);
    a2.x += bf2f(v2.x); a2.y += bf2f(v2.y); a2.z += bf2f(v2.z); a2.w += bf2f(v2.w);
    a3.x += bf2f(v3.x); a3.y += bf2f(v3.y); a3.z += bf2f(v3.z); a3.w += bf2f(v3.w);
  }
  for (; e < e1; ++e) {
    int s = csr[e];
    ushort4 v = *reinterpret_cast<const ushort4*>(&XW[(size_t)s * 128 + lane * 4]);
    a0.x += bf2f(v.x); a0.y += bf2f(v.y); a0.z += bf2f(v.z); a0.w += bf2f(v.w);
  }
  float4 acc;
  acc.x = (a0.x + a1.x) + (a2.x + a3.x);
  acc.y = (a0.y + a1.y) + (a2.y + a3.y);
  acc.z = (a0.z + a1.z) + (a2.z + a3.z);
  acc.w = (a0.w + a1.w) + (a2.w + a3.w);
  float sc = isr_in[node];
  float4 b = *reinterpret_cast<const float4*>(&bias[lane * 4]);
  float4 o;
  o.x = fmaxf(fmaf(acc.x, sc, b.x), 0.f);
  o.y = fmaxf(fmaf(acc.y, sc, b.y), 0.f);
  o.z = fmaxf(fmaf(acc.z, sc, b.z), 0.f);
  o.w = fmaxf(fmaf(acc.w, sc, b.w), 0.f);
  *reinterpret_cast<float4*>(&H[(size_t)node * 128 + lane * 4]) = o;
}

// out[col] += column sums of X[n, ncol]; out pre-zeroed. ncol | 256.
__global__ __launch_bounds__(256) void colsum_kernel(const float* __restrict__ X,
                                                     float* __restrict__ out, int n, int ncol) {
  __shared__ float s[256];
  int col = threadIdx.x % ncol;
  int rpb = 256 / ncol;
  int rb = threadIdx.x / ncol;
  float acc = 0.f;
  for (int r = blockIdx.x * rpb + rb; r < n; r += gridDim.x * rpb)
    acc += X[(size_t)r * ncol + col];
  s[threadIdx.x] = acc;
  __syncthreads();
  if (threadIdx.x < ncol) {
    float v = 0.f;
    for (int i = 0; i < rpb; ++i) v += s[threadIdx.x + i * ncol];
    atomicAdd(&out[col], v);
  }
}

// out[col] = max over rows (X >= 0 relu output; out pre-zeroed).
__global__ __launch_bounds__(256) void colmax_kernel(const float* __restrict__ X,
                                                     unsigned* __restrict__ out, int n, int ncol) {
  __shared__ float s[256];
  int col = threadIdx.x % ncol;
  int rpb = 256 / ncol;
  int rb = threadIdx.x / ncol;
  float acc = 0.f;
  for (int r = blockIdx.x * rpb + rb; r < n; r += gridDim.x * rpb)
    acc = fmaxf(acc, X[(size_t)r * ncol + col]);
  s[threadIdx.x] = acc;
  __syncthreads();
  if (threadIdx.x < ncol) {
    float v = s[threadIdx.x];
    for (int i = 1; i < rpb; ++i) v = fmaxf(v, s[threadIdx.x + i * ncol]);
    atomicMax(&out[col], __float_as_uint(v));
  }
}

// norm_embed(a) + norm_embed(f) then @ W_cls + b_cls. Single block of 128.
__global__ __launch_bounds__(128) void final_kernel(
    const float* __restrict__ emb_a_sum, const unsigned* __restrict__ emb_f_bits,
    const float* __restrict__ W_cls, const float* __restrict__ b_cls,
    float* __restrict__ out, float inv_n_apig, int ncls) {
  __shared__ float red[128];
  __shared__ float emb[128];
  int t = threadIdx.x;
  float a = emb_a_sum[t] * inv_n_apig;
  float f = __uint_as_float(emb_f_bits[t]);

  float vals[2] = {a, f};
  float norms[2];
#pragma unroll
  for (int which = 0; which < 2; ++which) {
    float x = vals[which];
    red[t] = x;
    __syncthreads();
    for (int o = 64; o > 0; o >>= 1) {
      if (t < o) red[t] += red[t + o];
      __syncthreads();
    }
    float mean = red[0] / 128.f;
    __syncthreads();
    float d = x - mean;
    red[t] = d * d;
    __syncthreads();
    for (int o = 64; o > 0; o >>= 1) {
      if (t < o) red[t] += red[t + o];
      __syncthreads();
    }
    float stdv = sqrtf(red[0] / 127.f);  // ddof=1
    __syncthreads();
    float z = d / stdv;
    red[t] = z;
    __syncthreads();
    for (int o = 64; o > 0; o >>= 1) {
      if (t < o) red[t] = fminf(red[t], red[t + o]);
      __syncthreads();
    }
    float zmin = red[0];
    __syncthreads();
    red[t] = z;
    __syncthreads();
    for (int o = 64; o > 0; o >>= 1) {
      if (t < o) red[t] = fmaxf(red[t], red[t + o]);
      __syncthreads();
    }
    float zmax = red[0];
    __syncthreads();
    norms[which] = (z - zmin) / (zmax - zmin);
  }

  emb[t] = norms[0] + norms[1];
  __syncthreads();
  if (t < ncls) {
    float acc = b_cls[t];
    for (int k = 0; k < 128; ++k) acc = fmaf(emb[k], W_cls[k * ncls + t], acc);
    out[t] = acc;
  }
}

extern "C" void kernel_launch(void* const* d_in, const int* in_sizes, int n_in,
                              void* d_out, int out_size, void* d_ws, size_t ws_size,
                              hipStream_t stream) {
  const float* apig_feat = (const float*)d_in[0];
  const float* fcg_feat = (const float*)d_in[1];
  const float* W_a1 = (const float*)d_in[2];
  const float* b_a1 = (const float*)d_in[3];
  const float* W_a2 = (const float*)d_in[4];
  const float* b_a2 = (const float*)d_in[5];
  const float* W_f1 = (const float*)d_in[6];
  const float* b_f1 = (const float*)d_in[7];
  const float* W_f2 = (const float*)d_in[8];
  const float* b_f2 = (const float*)d_in[9];
  const float* W1 = (const float*)d_in[10];
  const float* b1 = (const float*)d_in[11];
  const float* W2 = (const float*)d_in[12];
  const float* b2 = (const float*)d_in[13];
  // d_in[14]/d_in[15] (W_attn, b_attn): dead — softmax over length-1 axis == 1.
  const float* W_cls = (const float*)d_in[16];
  const float* b_cls = (const float*)d_in[17];
  const int* a_src = (const int*)d_in[18];
  const int* a_dst = (const int*)d_in[19];
  const int* f_src = (const int*)d_in[20];
  const int* f_dst = (const int*)d_in[21];

  const int hidden = in_sizes[3];             // 128
  const int united = in_sizes[11];            // 64
  const int ncls = in_sizes[17];              // 10
  const int apig_dim = in_sizes[2] / hidden;  // 256
  const int fcg_dim = in_sizes[6] / hidden;   // 128
  const int n_a = in_sizes[0] / apig_dim;     // 50000
  const int n_f = in_sizes[1] / fcg_dim;      // 100000
  const int e_a = in_sizes[18];               // 800000
  const int e_f = in_sizes[20];               // 1600000

  // ---- workspace carve-up (all 256B aligned) ----
  char* w = (char*)d_ws;
  auto alloc = [&](size_t bytes) -> void* {
    void* p = (void*)w;
    w += (bytes + 255) & ~(size_t)255;
    return p;
  };
  const int E_tot = e_a + e_f;
  const int B = (E_tot + SORT_T - 1) / SORT_T;

  float* isr_out_a = (float*)alloc((size_t)n_a * 4);
  float* isr_in_a = (float*)alloc((size_t)n_a * 4);
  float* isr_out_f = (float*)alloc((size_t)n_f * 4);
  float* isr_in_f = (float*)alloc((size_t)n_f * 4);
  int* offs_a = (int*)alloc((size_t)(n_a + 1) * 4);
  int* offs_f = (int*)alloc((size_t)(n_f + 1) * 4);
  int* offs_src_a = (int*)alloc((size_t)(n_a + 1) * 4);
  int* offs_src_f = (int*)alloc((size_t)(n_f + 1) * 4);
  int* k1 = (int*)alloc((size_t)E_tot * 4);   // phase-1 keys (dst, then reused for src)
  int* p1 = (int*)alloc((size_t)E_tot * 4);   // phase-1 payload (src values)
  int* csr = (int*)alloc((size_t)E_tot * 4);  // final CSR (apig [0,e_a), fcg [e_a,..))
  int* blkhist = (int*)alloc((size_t)512 * B * 4);
  int* binstart = (int*)alloc((size_t)512 * 4);
  unsigned short* G_a = (unsigned short*)alloc((size_t)n_a * hidden * 2);  // bf16 table
  float* H_a = (float*)alloc((size_t)n_a * hidden * 4);                    // h1 / a_dec / h2
  unsigned short* G_f = (unsigned short*)alloc((size_t)n_f * hidden * 2);
  float* H_f = (float*)alloc((size_t)n_f * hidden * 4);
  float* E_a = (float*)G_a;  // enc raw aliases G_a (disjoint lifetimes)
  float* E_f = (float*)G_f;
  float* a_sum = (float*)alloc((size_t)united * 4);
  float* f_sum = (float*)alloc((size_t)united * 4);
  float* emb_a = (float*)alloc((size_t)hidden * 4);
  unsigned* emb_f = (unsigned*)alloc((size_t)hidden * 4);
  int* csr_a = csr;
  int* csr_f = csr + e_a;
  (void)ws_size;
  (void)n_in;
  (void)out_size;

  dim3 blk(256);

  // ---- init tiny accumulators + offs sentinels ----
  zero_small_kernel<<<1, 128, 0, stream>>>(a_sum, f_sum, united, emb_a, emb_f, hidden,
                                           offs_a, offs_src_a, n_a, e_a,
                                           offs_f, offs_src_f, n_f, e_f);

  // ---- CSR build: dst sort (2-phase MSD) -> csr + offs ----
  radix_hist_kernel<<<B, blk, 0, stream>>>(a_dst, f_dst, e_a, E_tot, blkhist, B);
  radix_scatter_kernel<<<B, blk, 0, stream>>>(a_dst, f_dst, a_src, f_src, e_a, E_tot,
                                              blkhist, B, k1, p1, binstart);
  bucket_dst_kernel<<<512, blk, 0, stream>>>(k1, p1, binstart, E_tot, e_a,
                                             csr, offs_a, n_a, offs_f, n_f);
  // ---- src sort (2-phase, keys only) -> offs_src (out-degrees) ----
  radix_hist_kernel<<<B, blk, 0, stream>>>(a_src, f_src, e_a, E_tot, blkhist, B);
  radix_scatter_kernel<<<B, blk, 0, stream>>>(a_src, f_src, nullptr, nullptr, e_a, E_tot,
                                              blkhist, B, k1, nullptr, binstart);
  bucket_src_kernel<<<512, blk, 0, stream>>>(k1, binstart, E_tot, e_a,
                                             offs_src_a, n_a, offs_src_f, n_f);
  isr_kernel<<<(n_f + 255) / 256, blk, 0, stream>>>(offs_a, offs_src_a, isr_out_a, isr_in_a,
                                                    n_a, offs_f, offs_src_f, isr_out_f,
                                                    isr_in_f, n_f);

  const int ga = (n_a + 63) / 64, gf = (n_f + 63) / 64;

  // ---- apig conv1 + enc ----
  gemm_mfma_kernel<<<dim3(ga, hidden / 64), blk, 0, stream>>>(
      apig_feat, W_a1, G_a, n_a, hidden, apig_dim, nullptr, 0.f, isr_out_a, nullptr, 1);
  agg_kernel<<<(n_a + 7) / 8, blk, 0, stream>>>(G_a, offs_a, csr_a, isr_in_a, b_a1, H_a, n_a);
  gemm_mfma_kernel<<<dim3(ga, united / 64), blk, 0, stream>>>(
      H_a, W1, E_a, n_a, united, hidden, nullptr, 0.f, nullptr, b1, 0);  // E_a=G_a (dead)
  colsum_kernel<<<256, blk, 0, stream>>>(E_a, a_sum, n_a, united);

  // ---- fcg conv1 + enc ----
  gemm_mfma_kernel<<<dim3(gf, hidden / 64), blk, 0, stream>>>(
      fcg_feat, W_f1, G_f, n_f, hidden, fcg_dim, nullptr, 0.f, isr_out_f, nullptr, 1);
  agg_kernel<<<(n_f + 7) / 8, blk, 0, stream>>>(G_f, offs_f, csr_f, isr_in_f, b_f1, H_f, n_f);
  gemm_mfma_kernel<<<dim3(gf, united / 64), blk, 0, stream>>>(
      H_f, W1, E_f, n_f, united, hidden, nullptr, 0.f, nullptr, b1, 0);
  colsum_kernel<<<256, blk, 0, stream>>>(E_f, f_sum, n_f, united);

  // ---- apig dec + conv2 + mean ----
  gemm_mfma_kernel<<<dim3(ga, hidden / 64), blk, 0, stream>>>(
      E_a, W2, H_a, n_a, hidden, united, f_sum, 0.1f, nullptr, b2, 0);  // a_dec
  gemm_mfma_kernel<<<dim3(ga, hidden / 64), blk, 0, stream>>>(
      H_a, W_a2, G_a, n_a, hidden, hidden, nullptr, 0.f, isr_out_a, nullptr, 1);
  agg_kernel<<<(n_a + 7) / 8, blk, 0, stream>>>(G_a, offs_a, csr_a, isr_in_a, b_a2, H_a, n_a);
  colsum_kernel<<<256, blk, 0, stream>>>(H_a, emb_a, n_a, hidden);

  // ---- fcg dec + conv2 + max ----
  gemm_mfma_kernel<<<dim3(gf, hidden / 64), blk, 0, stream>>>(
      E_f, W2, H_f, n_f, hidden, united, a_sum, 0.1f, nullptr, b2, 0);  // f_dec
  gemm_mfma_kernel<<<dim3(gf, hidden / 64), blk, 0, stream>>>(
      H_f, W_f2, G_f, n_f, hidden, hidden, nullptr, 0.f, isr_out_f, nullptr, 1);
  agg_kernel<<<(n_f + 7) / 8, blk, 0, stream>>>(G_f, offs_f, csr_f, isr_in_f, b_f2, H_f, n_f);
  colmax_kernel<<<256, blk, 0, stream>>>(H_f, emb_f, n_f, hidden);

  // ---- head ----
  final_kernel<<<1, 128, 0, stream>>>(emb_a, emb_f, W_cls, b_cls, (float*)d_out,
                                      1.0f / (float)n_a, ncls);
}

// Round 9
// 786.405 us; speedup vs baseline: 1.2054x; 1.1870x over previous
//
#include <hip/hip_runtime.h>
#include <math.h>

// ---------------------------------------------------------------------------
// MultiGraphClassifier on MI355X.
// Pipeline: 2x GraphConv per graph + cross-graph fusion + tiny head.
// Strategy: ATOMIC-FREE CSR build via MSD radix bucketing (high 9 bits) +
// per-bucket LDS counting sort (low 9 bits); offs emitted directly from the
// bucket scans. Gather-side aggregation over bf16 tables; bf16-MFMA GEMMs
// with fp32 accumulate and fused epilogues.
// Note: softmax over a length-1 axis == 1.0, so emb = norm(a) + norm(f).
// R1: 3-phase scan. R3: atomic-free scatter. R4: bf16 MFMA + bf16 tables.
// R5: 4-wide agg unroll + dispatch fusion.
// R6/R7: FALSIFIED: atomic scope/sharding changes nothing — every global
//   atomic RMW costs a fixed memory-side transaction (~21 G/s ceiling).
// R8: radix sort removed global atomics (WRITE 159->21MB) but scatter ran at
//   5.8% occupancy (B=147 blocks @ SORT_T=16384) + O(512*B) redundant
//   in-block scan -> 108us x2. R9: SORT_T=4096 (B=586), decoupled
//   cursor/binscan kernels, packed single-int scatter payload (dst),
//   u16 scatter (src).
// ---------------------------------------------------------------------------

typedef __attribute__((ext_vector_type(8))) short bf16x8;
typedef __attribute__((ext_vector_type(4))) float f32x4;

#define SORT_T 4096  // edges per phase-1 block

static __device__ inline unsigned short f2bf(float f) {
  unsigned u = __float_as_uint(f);
  unsigned r = (u + 0x7fff + ((u >> 16) & 1)) >> 16;  // RNE
  return (unsigned short)r;
}
static __device__ inline float bf2f(unsigned short h) {
  return __uint_as_float(((unsigned)h) << 16);
}

// Zero tiny accumulators + write offs sentinels. One block of 128.
__global__ void zero_small_kernel(float* __restrict__ s0, float* __restrict__ s1, int ns,
                                  float* __restrict__ ea, unsigned* __restrict__ ef, int ne,
                                  int* __restrict__ offs_a, int* __restrict__ offs_src_a,
                                  int n_a, int e_a,
                                  int* __restrict__ offs_f, int* __restrict__ offs_src_f,
                                  int n_f, int e_f) {
  int i = threadIdx.x;
  if (i < ns) { s0[i] = 0.f; s1[i] = 0.f; }
  if (i < ne) { ea[i] = 0.f; ef[i] = 0u; }
  if (i == 0) {
    offs_a[n_a] = e_a;
    offs_src_a[n_a] = e_a;
    offs_f[n_f] = e_f;
    offs_src_f[n_f] = e_f;
  }
}

// Combined key at edge i: apig -> key, fcg -> key + 65536 (18-bit space).
static __device__ inline int edge_key(const int* __restrict__ a_key,
                                      const int* __restrict__ f_key, int e_a, int i) {
  return (i < e_a) ? a_key[i] : (f_key[i - e_a] + 65536);
}

// Phase-1 histogram over high 9 bits. LDS atomics only.
__global__ __launch_bounds__(256) void radix_hist_kernel(
    const int* __restrict__ a_key, const int* __restrict__ f_key, int e_a, int E,
    int* __restrict__ blkhist, int B) {
  __shared__ int h[512];
  for (int i = threadIdx.x; i < 512; i += 256) h[i] = 0;
  __syncthreads();
  int base = blockIdx.x * SORT_T;
  int end = base + SORT_T;
  if (end > E) end = E;
  for (int i = base + threadIdx.x; i < end; i += 256)
    atomicAdd(&h[edge_key(a_key, f_key, e_a, i) >> 9], 1);
  __syncthreads();
  for (int i = threadIdx.x; i < 512; i += 256) blkhist[i * B + blockIdx.x] = h[i];
}

// One block per bin: exclusive prefix over the bin's B block-counts (in
// place) + bin total.
__global__ __launch_bounds__(256) void cursor_kernel(int* __restrict__ blkhist, int B,
                                                     int* __restrict__ bintotal) {
  __shared__ int part[256];
  int* row = blkhist + (size_t)blockIdx.x * B;
  int C = (B + 255) / 256;
  int start = threadIdx.x * C;
  int end = start + C;
  if (end > B) end = B;
  int v[8];  // C <= 8 for B <= 2048
  int s = 0;
  for (int j = start; j < end; ++j) {
    v[j - start] = row[j];
    s += v[j - start];
  }
  part[threadIdx.x] = s;
  __syncthreads();
  for (int o = 1; o < 256; o <<= 1) {
    int u = (threadIdx.x >= o) ? part[threadIdx.x - o] : 0;
    __syncthreads();
    part[threadIdx.x] += u;
    __syncthreads();
  }
  int run = part[threadIdx.x] - s;  // exclusive
  for (int j = start; j < end; ++j) {
    row[j] = run;
    run += v[j - start];
  }
  if (threadIdx.x == 255) bintotal[blockIdx.x] = part[255];
}

// Exclusive scan of 512 bin totals -> binstart. One block of 256.
__global__ __launch_bounds__(256) void binscan_kernel(const int* __restrict__ bintotal,
                                                      int* __restrict__ binstart) {
  __shared__ int x[512];
  x[threadIdx.x] = bintotal[threadIdx.x];
  x[threadIdx.x + 256] = bintotal[threadIdx.x + 256];
  __syncthreads();
  for (int o = 1; o < 512; o <<= 1) {
    int i0 = threadIdx.x, i1 = threadIdx.x + 256;
    int v0 = (i0 >= o) ? x[i0 - o] : 0;
    int v1 = (i1 >= o) ? x[i1 - o] : 0;
    __syncthreads();
    x[i0] += v0;
    x[i1] += v1;
    __syncthreads();
  }
  binstart[threadIdx.x] = x[threadIdx.x] - bintotal[threadIdx.x];
  binstart[threadIdx.x + 256] = x[threadIdx.x + 256] - bintotal[threadIdx.x + 256];
}

// Phase-1 scatter (dst): packed output (low9<<17 | src), cursors precomputed.
__global__ __launch_bounds__(256) void scatter_dst_kernel(
    const int* __restrict__ a_key, const int* __restrict__ f_key,
    const int* __restrict__ a_pay, const int* __restrict__ f_pay,
    int e_a, int E, const int* __restrict__ blkhist, int B,
    const int* __restrict__ binstart, int* __restrict__ opack) {
  __shared__ int cur[512];
  int b = blockIdx.x;
  for (int bin = threadIdx.x; bin < 512; bin += 256)
    cur[bin] = binstart[bin] + blkhist[bin * B + b];
  __syncthreads();
  int base = b * SORT_T;
  int end = base + SORT_T;
  if (end > E) end = E;
  for (int i = base + threadIdx.x; i < end; i += 256) {
    int k = edge_key(a_key, f_key, e_a, i);
    int pay = (i < e_a) ? a_pay[i] : f_pay[i - e_a];
    int pos = atomicAdd(&cur[k >> 9], 1);
    opack[pos] = ((k & 511) << 17) | pay;
  }
}

// Phase-1 scatter (src): u16 low-key only.
__global__ __launch_bounds__(256) void scatter_src_kernel(
    const int* __restrict__ a_key, const int* __restrict__ f_key,
    int e_a, int E, const int* __restrict__ blkhist, int B,
    const int* __restrict__ binstart, unsigned short* __restrict__ okey) {
  __shared__ int cur[512];
  int b = blockIdx.x;
  for (int bin = threadIdx.x; bin < 512; bin += 256)
    cur[bin] = binstart[bin] + blkhist[bin * B + b];
  __syncthreads();
  int base = b * SORT_T;
  int end = base + SORT_T;
  if (end > E) end = E;
  for (int i = base + threadIdx.x; i < end; i += 256) {
    int k = edge_key(a_key, f_key, e_a, i);
    int pos = atomicAdd(&cur[k >> 9], 1);
    okey[pos] = (unsigned short)(k & 511);
  }
}

// Phase-2 (dst): per-bucket LDS counting sort over low 9 bits. Writes csr
// (payload) at final positions and offs for the bucket's 512 node keys.
__global__ __launch_bounds__(256) void bucket_dst_kernel(
    const int* __restrict__ kp, const int* __restrict__ binstart, int E, int e_a,
    int* __restrict__ csr, int* __restrict__ offs_a, int n_a,
    int* __restrict__ offs_f, int n_f) {
  __shared__ int h[512], x[512], cur[512];
  int b = blockIdx.x;
  int s = binstart[b];
  int e = (b == 511) ? E : binstart[b + 1];
  for (int i = threadIdx.x; i < 512; i += 256) h[i] = 0;
  __syncthreads();
  for (int i = s + threadIdx.x; i < e; i += 256) atomicAdd(&h[kp[i] >> 17], 1);
  __syncthreads();
  for (int i = threadIdx.x; i < 512; i += 256) x[i] = h[i];
  __syncthreads();
  for (int o = 1; o < 512; o <<= 1) {
    int i0 = threadIdx.x, i1 = threadIdx.x + 256;
    int v0 = (i0 >= o) ? x[i0 - o] : 0;
    int v1 = (i1 >= o) ? x[i1 - o] : 0;
    __syncthreads();
    x[i0] += v0;
    x[i1] += v1;
    __syncthreads();
  }
  for (int low = threadIdx.x; low < 512; low += 256) {
    int gpos = s + x[low] - h[low];  // exclusive start of this key's run
    cur[low] = gpos;
    int key = (b << 9) | low;
    if (key < 65536) {
      if (key < n_a) offs_a[key] = gpos;
    } else {
      int v = key - 65536;
      if (v < n_f) offs_f[v] = gpos - e_a;
    }
  }
  __syncthreads();
  for (int i = s + threadIdx.x; i < e; i += 256) {
    int pv = kp[i];
    int pos = atomicAdd(&cur[pv >> 17], 1);
    csr[pos] = pv & 0x1FFFF;
  }
}

// Phase-2 (src): histogram + scan only -> offs_src (out-degree boundaries).
__global__ __launch_bounds__(256) void bucket_src_kernel(
    const unsigned short* __restrict__ kl, const int* __restrict__ binstart, int E, int e_a,
    int* __restrict__ offs_src_a, int n_a, int* __restrict__ offs_src_f, int n_f) {
  __shared__ int h[512], x[512];
  int b = blockIdx.x;
  int s = binstart[b];
  int e = (b == 511) ? E : binstart[b + 1];
  for (int i = threadIdx.x; i < 512; i += 256) h[i] = 0;
  __syncthreads();
  for (int i = s + threadIdx.x; i < e; i += 256) atomicAdd(&h[kl[i]], 1);
  __syncthreads();
  for (int i = threadIdx.x; i < 512; i += 256) x[i] = h[i];
  __syncthreads();
  for (int o = 1; o < 512; o <<= 1) {
    int i0 = threadIdx.x, i1 = threadIdx.x + 256;
    int v0 = (i0 >= o) ? x[i0 - o] : 0;
    int v1 = (i1 >= o) ? x[i1 - o] : 0;
    __syncthreads();
    x[i0] += v0;
    x[i1] += v1;
    __syncthreads();
  }
  for (int low = threadIdx.x; low < 512; low += 256) {
    int gpos = s + x[low] - h[low];
    int key = (b << 9) | low;
    if (key < 65536) {
      if (key < n_a) offs_src_a[key] = gpos;
    } else {
      int v = key - 65536;
      if (v < n_f) offs_src_f[v] = gpos - e_a;
    }
  }
}

// isr from offs diffs (needs sentinels).
__global__ void isr_kernel(const int* __restrict__ offs_a, const int* __restrict__ offs_src_a,
                           float* __restrict__ io_a, float* __restrict__ ii_a, int n_a,
                           const int* __restrict__ offs_f, const int* __restrict__ offs_src_f,
                           float* __restrict__ io_f, float* __restrict__ ii_f, int n_f) {
  int i = blockIdx.x * blockDim.x + threadIdx.x;
  if (i < n_a) {
    int ci = offs_a[i + 1] - offs_a[i];
    int co = offs_src_a[i + 1] - offs_src_a[i];
    ii_a[i] = 1.0f / sqrtf((float)(ci < 1 ? 1 : ci));
    io_a[i] = 1.0f / sqrtf((float)(co < 1 ? 1 : co));
  }
  if (i < n_f) {
    int ci = offs_f[i + 1] - offs_f[i];
    int co = offs_src_f[i + 1] - offs_src_f[i];
    ii_f[i] = 1.0f / sqrtf((float)(ci < 1 ? 1 : ci));
    io_f[i] = 1.0f / sqrtf((float)(co < 1 ? 1 : co));
  }
}

// ---------------------------------------------------------------------------
// bf16-MFMA GEMM: C[M,N] = epi( (A[M,K](+s*add_vec[K])) @ B[K,N] )
// fp32 global inputs cast bf16 in LDS staging; fp32 MFMA accumulate.
// epi: *rowscale[M]?  +bias[N]?  out bf16 or fp32. N%64==0, K%64==0.
// ---------------------------------------------------------------------------
#define LDT 72
__global__ __launch_bounds__(256) void gemm_mfma_kernel(
    const float* __restrict__ A, const float* __restrict__ B, void* __restrict__ C,
    int M, int N, int K,
    const float* __restrict__ add_vec, float add_scale,
    const float* __restrict__ rowscale, const float* __restrict__ bias, int out_bf16) {
  __shared__ __align__(16) short As[64 * LDT];  // [m][k]
  __shared__ __align__(16) short Bs[64 * LDT];  // [n][k] (transposed)
  const int m0 = blockIdx.x * 64, n0 = blockIdx.y * 64;
  const int tid = threadIdx.x;
  const int lane = tid & 63, w = tid >> 6;
  const int q = lane >> 4, l16 = lane & 15;
  const int srow = tid >> 2, schunk = (tid & 3) * 16;
  f32x4 acc[4] = {};
  for (int k0 = 0; k0 < K; k0 += 64) {
    {
      int m = m0 + srow;
      float tmp[16];
      if (m < M) {
        const float* s = A + (size_t)m * K + k0 + schunk;
#pragma unroll
        for (int i = 0; i < 16; i += 4) {
          float4 v = *reinterpret_cast<const float4*>(s + i);
          tmp[i] = v.x; tmp[i + 1] = v.y; tmp[i + 2] = v.z; tmp[i + 3] = v.w;
        }
        if (add_vec) {
#pragma unroll
          for (int i = 0; i < 16; ++i) tmp[i] += add_scale * add_vec[k0 + schunk + i];
        }
      } else {
#pragma unroll
        for (int i = 0; i < 16; ++i) tmp[i] = 0.f;
      }
#pragma unroll
      for (int i = 0; i < 16; ++i) As[srow * LDT + schunk + i] = (short)f2bf(tmp[i]);
    }
    {
      const float* s = B + (size_t)(k0 + srow) * N + n0 + schunk;
#pragma unroll
      for (int i = 0; i < 16; i += 4) {
        float4 v = *reinterpret_cast<const float4*>(s + i);
        Bs[(schunk + i + 0) * LDT + srow] = (short)f2bf(v.x);
        Bs[(schunk + i + 1) * LDT + srow] = (short)f2bf(v.y);
        Bs[(schunk + i + 2) * LDT + srow] = (short)f2bf(v.z);
        Bs[(schunk + i + 3) * LDT + srow] = (short)f2bf(v.w);
      }
    }
    __syncthreads();
#pragma unroll
    for (int kk = 0; kk < 2; ++kk) {
      bf16x8 af = *reinterpret_cast<const bf16x8*>(&As[(w * 16 + l16) * LDT + kk * 32 + q * 8]);
#pragma unroll
      for (int nt = 0; nt < 4; ++nt) {
        bf16x8 bf = *reinterpret_cast<const bf16x8*>(&Bs[(nt * 16 + l16) * LDT + kk * 32 + q * 8]);
        acc[nt] = __builtin_amdgcn_mfma_f32_16x16x32_bf16(af, bf, acc[nt], 0, 0, 0);
      }
    }
    __syncthreads();
  }
#pragma unroll
  for (int nt = 0; nt < 4; ++nt) {
    int gcol = n0 + nt * 16 + l16;
    float bv = bias ? bias[gcol] : 0.f;
#pragma unroll
    for (int r = 0; r < 4; ++r) {
      int grow = m0 + w * 16 + q * 4 + r;
      if (grow < M) {
        float v = acc[nt][r];
        if (rowscale) v *= rowscale[grow];
        v += bv;
        if (out_bf16)
          ((unsigned short*)C)[(size_t)grow * N + gcol] = f2bf(v);
        else
          ((float*)C)[(size_t)grow * N + gcol] = v;
      }
    }
  }
}

// H[node] = relu( (sum_{e in CSR[node]} XW_bf16[src(e)]) * isr_in[node] + b )
// 32 threads per node, 8 nodes/block, 4-wide unroll (4 row loads in flight).
__global__ __launch_bounds__(256) void agg_kernel(
    const unsigned short* __restrict__ XW, const int* __restrict__ offs,
    const int* __restrict__ csr, const float* __restrict__ isr_in,
    const float* __restrict__ bias, float* __restrict__ H, int n) {
  int lane = threadIdx.x & 31;
  int node = blockIdx.x * 8 + (threadIdx.x >> 5);
  if (node >= n) return;
  int e0 = offs[node], e1 = offs[node + 1];
  float4 a0 = make_float4(0.f, 0.f, 0.f, 0.f);
  float4 a1 = a0, a2 = a0, a3 = a0;
  int e = e0;
  for (; e + 4 <= e1; e += 4) {
    int s0 = csr[e], s1 = csr[e + 1], s2 = csr[e + 2], s3 = csr[e + 3];
    ushort4 v0 = *reinterpret_cast<const ushort4*>(&XW[(size_t)s0 * 128 + lane * 4]);
    ushort4 v1 = *reinterpret_cast<const ushort4*>(&XW[(size_t)s1 * 128 + lane * 4]);
    ushort4 v2 = *reinterpret_cast<const ushort4*>(&XW[(size_t)s2 * 128 + lane * 4]);
    ushort4 v3 = *reinterpret_cast<const ushort4*>(&XW[(size_t)s3 * 128 + lane * 4]);
    a0.x += bf2f(v0.x); a0.y += bf2f(v0.y); a0.z += bf2f(v0.z); a0.w += bf2f(v0.w);
    a1.x += bf2f(v1.x); a1.y += bf2f(v1.y); a1.z += bf2f(v1.z); a1.w += bf2f(v1.w);
    a2.x += bf2f(v2.x); a2.y += bf2f(v2.y); a2.z += bf2f(v2.z); a2.w += bf2f(v2.w);
    a3.x += bf2f(v3.x); a3.y += bf2f(v3.y); a3.z += bf2f(v3.z); a3.w += bf2f(v3.w);
  }
  for (; e < e1; ++e) {
    int s = csr[e];
    ushort4 v = *reinterpret_cast<const ushort4*>(&XW[(size_t)s * 128 + lane * 4]);
    a0.x += bf2f(v.x); a0.y += bf2f(v.y); a0.z += bf2f(v.z); a0.w += bf2f(v.w);
  }
  float4 acc;
  acc.x = (a0.x + a1.x) + (a2.x + a3.x);
  acc.y = (a0.y + a1.y) + (a2.y + a3.y);
  acc.z = (a0.z + a1.z) + (a2.z + a3.z);
  acc.w = (a0.w + a1.w) + (a2.w + a3.w);
  float sc = isr_in[node];
  float4 b = *reinterpret_cast<const float4*>(&bias[lane * 4]);
  float4 o;
  o.x = fmaxf(fmaf(acc.x, sc, b.x), 0.f);
  o.y = fmaxf(fmaf(acc.y, sc, b.y), 0.f);
  o.z = fmaxf(fmaf(acc.z, sc, b.z), 0.f);
  o.w = fmaxf(fmaf(acc.w, sc, b.w), 0.f);
  *reinterpret_cast<float4*>(&H[(size_t)node * 128 + lane * 4]) = o;
}

// out[col] += column sums of X[n, ncol]; out pre-zeroed. ncol | 256.
__global__ __launch_bounds__(256) void colsum_kernel(const float* __restrict__ X,
                                                     float* __restrict__ out, int n, int ncol) {
  __shared__ float s[256];
  int col = threadIdx.x % ncol;
  int rpb = 256 / ncol;
  int rb = threadIdx.x / ncol;
  float acc = 0.f;
  for (int r = blockIdx.x * rpb + rb; r < n; r += gridDim.x * rpb)
    acc += X[(size_t)r * ncol + col];
  s[threadIdx.x] = acc;
  __syncthreads();
  if (threadIdx.x < ncol) {
    float v = 0.f;
    for (int i = 0; i < rpb; ++i) v += s[threadIdx.x + i * ncol];
    atomicAdd(&out[col], v);
  }
}

// out[col] = max over rows (X >= 0 relu output; out pre-zeroed).
__global__ __launch_bounds__(256) void colmax_kernel(const float* __restrict__ X,
                                                     unsigned* __restrict__ out, int n, int ncol) {
  __shared__ float s[256];
  int col = threadIdx.x % ncol;
  int rpb = 256 / ncol;
  int rb = threadIdx.x / ncol;
  float acc = 0.f;
  for (int r = blockIdx.x * rpb + rb; r < n; r += gridDim.x * rpb)
    acc = fmaxf(acc, X[(size_t)r * ncol + col]);
  s[threadIdx.x] = acc;
  __syncthreads();
  if (threadIdx.x < ncol) {
    float v = s[threadIdx.x];
    for (int i = 1; i < rpb; ++i) v = fmaxf(v, s[threadIdx.x + i * ncol]);
    atomicMax(&out[col], __float_as_uint(v));
  }
}

// norm_embed(a) + norm_embed(f) then @ W_cls + b_cls. Single block of 128.
__global__ __launch_bounds__(128) void final_kernel(
    const float* __restrict__ emb_a_sum, const unsigned* __restrict__ emb_f_bits,
    const float* __restrict__ W_cls, const float* __restrict__ b_cls,
    float* __restrict__ out, float inv_n_apig, int ncls) {
  __shared__ float red[128];
  __shared__ float emb[128];
  int t = threadIdx.x;
  float a = emb_a_sum[t] * inv_n_apig;
  float f = __uint_as_float(emb_f_bits[t]);

  float vals[2] = {a, f};
  float norms[2];
#pragma unroll
  for (int which = 0; which < 2; ++which) {
    float x = vals[which];
    red[t] = x;
    __syncthreads();
    for (int o = 64; o > 0; o >>= 1) {
      if (t < o) red[t] += red[t + o];
      __syncthreads();
    }
    float mean = red[0] / 128.f;
    __syncthreads();
    float d = x - mean;
    red[t] = d * d;
    __syncthreads();
    for (int o = 64; o > 0; o >>= 1) {
      if (t < o) red[t] += red[t + o];
      __syncthreads();
    }
    float stdv = sqrtf(red[0] / 127.f);  // ddof=1
    __syncthreads();
    float z = d / stdv;
    red[t] = z;
    __syncthreads();
    for (int o = 64; o > 0; o >>= 1) {
      if (t < o) red[t] = fminf(red[t], red[t + o]);
      __syncthreads();
    }
    float zmin = red[0];
    __syncthreads();
    red[t] = z;
    __syncthreads();
    for (int o = 64; o > 0; o >>= 1) {
      if (t < o) red[t] = fmaxf(red[t], red[t + o]);
      __syncthreads();
    }
    float zmax = red[0];
    __syncthreads();
    norms[which] = (z - zmin) / (zmax - zmin);
  }

  emb[t] = norms[0] + norms[1];
  __syncthreads();
  if (t < ncls) {
    float acc = b_cls[t];
    for (int k = 0; k < 128; ++k) acc = fmaf(emb[k], W_cls[k * ncls + t], acc);
    out[t] = acc;
  }
}

extern "C" void kernel_launch(void* const* d_in, const int* in_sizes, int n_in,
                              void* d_out, int out_size, void* d_ws, size_t ws_size,
                              hipStream_t stream) {
  const float* apig_feat = (const float*)d_in[0];
  const float* fcg_feat = (const float*)d_in[1];
  const float* W_a1 = (const float*)d_in[2];
  const float* b_a1 = (const float*)d_in[3];
  const float* W_a2 = (const float*)d_in[4];
  const float* b_a2 = (const float*)d_in[5];
  const float* W_f1 = (const float*)d_in[6];
  const float* b_f1 = (const float*)d_in[7];
  const float* W_f2 = (const float*)d_in[8];
  const float* b_f2 = (const float*)d_in[9];
  const float* W1 = (const float*)d_in[10];
  const float* b1 = (const float*)d_in[11];
  const float* W2 = (const float*)d_in[12];
  const float* b2 = (const float*)d_in[13];
  // d_in[14]/d_in[15] (W_attn, b_attn): dead — softmax over length-1 axis == 1.
  const float* W_cls = (const float*)d_in[16];
  const float* b_cls = (const float*)d_in[17];
  const int* a_src = (const int*)d_in[18];
  const int* a_dst = (const int*)d_in[19];
  const int* f_src = (const int*)d_in[20];
  const int* f_dst = (const int*)d_in[21];

  const int hidden = in_sizes[3];             // 128
  const int united = in_sizes[11];            // 64
  const int ncls = in_sizes[17];              // 10
  const int apig_dim = in_sizes[2] / hidden;  // 256
  const int fcg_dim = in_sizes[6] / hidden;   // 128
  const int n_a = in_sizes[0] / apig_dim;     // 50000
  const int n_f = in_sizes[1] / fcg_dim;      // 100000
  const int e_a = in_sizes[18];               // 800000
  const int e_f = in_sizes[20];               // 1600000

  // ---- workspace carve-up (all 256B aligned) ----
  char* w = (char*)d_ws;
  auto alloc = [&](size_t bytes) -> void* {
    void* p = (void*)w;
    w += (bytes + 255) & ~(size_t)255;
    return p;
  };
  const int E_tot = e_a + e_f;
  const int B = (E_tot + SORT_T - 1) / SORT_T;

  float* isr_out_a = (float*)alloc((size_t)n_a * 4);
  float* isr_in_a = (float*)alloc((size_t)n_a * 4);
  float* isr_out_f = (float*)alloc((size_t)n_f * 4);
  float* isr_in_f = (float*)alloc((size_t)n_f * 4);
  int* offs_a = (int*)alloc((size_t)(n_a + 1) * 4);
  int* offs_f = (int*)alloc((size_t)(n_f + 1) * 4);
  int* offs_src_a = (int*)alloc((size_t)(n_a + 1) * 4);
  int* offs_src_f = (int*)alloc((size_t)(n_f + 1) * 4);
  int* kp = (int*)alloc((size_t)E_tot * 4);   // packed dst-sort output; u16 src reuses
  int* csr = (int*)alloc((size_t)E_tot * 4);  // final CSR (apig [0,e_a), fcg [e_a,..))
  int* blkhist = (int*)alloc((size_t)512 * B * 4);
  int* bintotal = (int*)alloc((size_t)512 * 4);
  int* binstart = (int*)alloc((size_t)512 * 4);
  unsigned short* G_a = (unsigned short*)alloc((size_t)n_a * hidden * 2);  // bf16 table
  float* H_a = (float*)alloc((size_t)n_a * hidden * 4);                    // h1 / a_dec / h2
  unsigned short* G_f = (unsigned short*)alloc((size_t)n_f * hidden * 2);
  float* H_f = (float*)alloc((size_t)n_f * hidden * 4);
  float* E_a = (float*)G_a;  // enc raw aliases G_a (disjoint lifetimes)
  float* E_f = (float*)G_f;
  float* a_sum = (float*)alloc((size_t)united * 4);
  float* f_sum = (float*)alloc((size_t)united * 4);
  float* emb_a = (float*)alloc((size_t)hidden * 4);
  unsigned* emb_f = (unsigned*)alloc((size_t)hidden * 4);
  int* csr_a = csr;
  int* csr_f = csr + e_a;
  unsigned short* ks = (unsigned short*)kp;  // src-sort u16 keys (after dst sort done)
  (void)ws_size;
  (void)n_in;
  (void)out_size;

  dim3 blk(256);

  // ---- init tiny accumulators + offs sentinels ----
  zero_small_kernel<<<1, 128, 0, stream>>>(a_sum, f_sum, united, emb_a, emb_f, hidden,
                                           offs_a, offs_src_a, n_a, e_a,
                                           offs_f, offs_src_f, n_f, e_f);

  // ---- CSR build: dst sort (hist -> cursor -> binscan -> scatter -> bucket) ----
  radix_hist_kernel<<<B, blk, 0, stream>>>(a_dst, f_dst, e_a, E_tot, blkhist, B);
  cursor_kernel<<<512, blk, 0, stream>>>(blkhist, B, bintotal);
  binscan_kernel<<<1, blk, 0, stream>>>(bintotal, binstart);
  scatter_dst_kernel<<<B, blk, 0, stream>>>(a_dst, f_dst, a_src, f_src, e_a, E_tot,
                                            blkhist, B, binstart, kp);
  bucket_dst_kernel<<<512, blk, 0, stream>>>(kp, binstart, E_tot, e_a,
                                             csr, offs_a, n_a, offs_f, n_f);
  // ---- src sort (keys only) -> offs_src (out-degrees) ----
  radix_hist_kernel<<<B, blk, 0, stream>>>(a_src, f_src, e_a, E_tot, blkhist, B);
  cursor_kernel<<<512, blk, 0, stream>>>(blkhist, B, bintotal);
  binscan_kernel<<<1, blk, 0, stream>>>(bintotal, binstart);
  scatter_src_kernel<<<B, blk, 0, stream>>>(a_src, f_src, e_a, E_tot, blkhist, B,
                                            binstart, ks);
  bucket_src_kernel<<<512, blk, 0, stream>>>(ks, binstart, E_tot, e_a,
                                             offs_src_a, n_a, offs_src_f, n_f);
  isr_kernel<<<(n_f + 255) / 256, blk, 0, stream>>>(offs_a, offs_src_a, isr_out_a, isr_in_a,
                                                    n_a, offs_f, offs_src_f, isr_out_f,
                                                    isr_in_f, n_f);

  const int ga = (n_a + 63) / 64, gf = (n_f + 63) / 64;

  // ---- apig conv1 + enc ----
  gemm_mfma_kernel<<<dim3(ga, hidden / 64), blk, 0, stream>>>(
      apig_feat, W_a1, G_a, n_a, hidden, apig_dim, nullptr, 0.f, isr_out_a, nullptr, 1);
  agg_kernel<<<(n_a + 7) / 8, blk, 0, stream>>>(G_a, offs_a, csr_a, isr_in_a, b_a1, H_a, n_a);
  gemm_mfma_kernel<<<dim3(ga, united / 64), blk, 0, stream>>>(
      H_a, W1, E_a, n_a, united, hidden, nullptr, 0.f, nullptr, b1, 0);  // E_a=G_a (dead)
  colsum_kernel<<<256, blk, 0, stream>>>(E_a, a_sum, n_a, united);

  // ---- fcg conv1 + enc ----
  gemm_mfma_kernel<<<dim3(gf, hidden / 64), blk, 0, stream>>>(
      fcg_feat, W_f1, G_f, n_f, hidden, fcg_dim, nullptr, 0.f, isr_out_f, nullptr, 1);
  agg_kernel<<<(n_f + 7) / 8, blk, 0, stream>>>(G_f, offs_f, csr_f, isr_in_f, b_f1, H_f, n_f);
  gemm_mfma_kernel<<<dim3(gf, united / 64), blk, 0, stream>>>(
      H_f, W1, E_f, n_f, united, hidden, nullptr, 0.f, nullptr, b1, 0);
  colsum_kernel<<<256, blk, 0, stream>>>(E_f, f_sum, n_f, united);

  // ---- apig dec + conv2 + mean ----
  gemm_mfma_kernel<<<dim3(ga, hidden / 64), blk, 0, stream>>>(
      E_a, W2, H_a, n_a, hidden, united, f_sum, 0.1f, nullptr, b2, 0);  // a_dec
  gemm_mfma_kernel<<<dim3(ga, hidden / 64), blk, 0, stream>>>(
      H_a, W_a2, G_a, n_a, hidden, hidden, nullptr, 0.f, isr_out_a, nullptr, 1);
  agg_kernel<<<(n_a + 7) / 8, blk, 0, stream>>>(G_a, offs_a, csr_a, isr_in_a, b_a2, H_a, n_a);
  colsum_kernel<<<256, blk, 0, stream>>>(H_a, emb_a, n_a, hidden);

  // ---- fcg dec + conv2 + max ----
  gemm_mfma_kernel<<<dim3(gf, hidden / 64), blk, 0, stream>>>(
      E_f, W2, H_f, n_f, hidden, united, a_sum, 0.1f, nullptr, b2, 0);  // f_dec
  gemm_mfma_kernel<<<dim3(gf, hidden / 64), blk, 0, stream>>>(
      H_f, W_f2, G_f, n_f, hidden, hidden, nullptr, 0.f, isr_out_f, nullptr, 1);
  agg_kernel<<<(n_f + 7) / 8, blk, 0, stream>>>(G_f, offs_f, csr_f, isr_in_f, b_f2, H_f, n_f);
  colmax_kernel<<<256, blk, 0, stream>>>(H_f, emb_f, n_f, hidden);

  // ---- head ----
  final_kernel<<<1, 128, 0, stream>>>(emb_a, emb_f, W_cls, b_cls, (float*)d_out,
                                      1.0f / (float)n_a, ncls);
}

// Round 10
// 707.049 us; speedup vs baseline: 1.3407x; 1.1122x over previous
//
#include <hip/hip_runtime.h>
#include <math.h>

// ---------------------------------------------------------------------------
// MultiGraphClassifier on MI355X.
// Pipeline: 2x GraphConv per graph + cross-graph fusion + tiny head.
// Strategy: ATOMIC-FREE CSR build via MSD radix bucketing + per-bucket LDS
// counting sort; gather-side aggregation over bf16 tables; bf16-MFMA GEMMs
// (bf16 A-input path) with fp32 accumulate and fused epilogues. All node
// intermediates (G,H,E,dec) bf16 — GEMM staging casts to bf16 anyway, so
// bf16 storage is bit-identical on the matmul path and halves traffic.
// conv2's H is never materialized: agg reduces per-block channel partials
// (sum/max) into a small P matrix, reduced by colsum/colmax.
// Note: softmax over a length-1 axis == 1.0, so emb = norm(a) + norm(f).
// R1: 3-phase scan. R3: atomic-free scatter. R4: bf16 MFMA + bf16 tables.
// R5: 4-wide agg unroll. R6/R7 FALSIFIED: global-atomic scope/sharding is
//   irrelevant — fixed ~21G/s memory-side RMW ceiling. R8: radix sort (no
//   global atomics). R9: SORT_T=4096 + decoupled cursor scan (786us).
// R10: bf16 intermediates + fused conv2 reductions (~345MB traffic removed).
// ---------------------------------------------------------------------------

typedef __attribute__((ext_vector_type(8))) short bf16x8;
typedef __attribute__((ext_vector_type(8))) unsigned short u16x8;
typedef __attribute__((ext_vector_type(4))) float f32x4;

#define SORT_T 4096  // edges per phase-1 block

static __device__ inline unsigned short f2bf(float f) {
  unsigned u = __float_as_uint(f);
  unsigned r = (u + 0x7fff + ((u >> 16) & 1)) >> 16;  // RNE
  return (unsigned short)r;
}
static __device__ inline float bf2f(unsigned short h) {
  return __uint_as_float(((unsigned)h) << 16);
}

// Zero tiny accumulators + write offs sentinels. One block of 128.
__global__ void zero_small_kernel(float* __restrict__ s0, float* __restrict__ s1, int ns,
                                  float* __restrict__ ea, unsigned* __restrict__ ef, int ne,
                                  int* __restrict__ offs_a, int* __restrict__ offs_src_a,
                                  int n_a, int e_a,
                                  int* __restrict__ offs_f, int* __restrict__ offs_src_f,
                                  int n_f, int e_f) {
  int i = threadIdx.x;
  if (i < ns) { s0[i] = 0.f; s1[i] = 0.f; }
  if (i < ne) { ea[i] = 0.f; ef[i] = 0u; }
  if (i == 0) {
    offs_a[n_a] = e_a;
    offs_src_a[n_a] = e_a;
    offs_f[n_f] = e_f;
    offs_src_f[n_f] = e_f;
  }
}

// Combined key at edge i: apig -> key, fcg -> key + 65536 (18-bit space).
static __device__ inline int edge_key(const int* __restrict__ a_key,
                                      const int* __restrict__ f_key, int e_a, int i) {
  return (i < e_a) ? a_key[i] : (f_key[i - e_a] + 65536);
}

// Phase-1 histogram over high 9 bits. LDS atomics only.
__global__ __launch_bounds__(256) void radix_hist_kernel(
    const int* __restrict__ a_key, const int* __restrict__ f_key, int e_a, int E,
    int* __restrict__ blkhist, int B) {
  __shared__ int h[512];
  for (int i = threadIdx.x; i < 512; i += 256) h[i] = 0;
  __syncthreads();
  int base = blockIdx.x * SORT_T;
  int end = base + SORT_T;
  if (end > E) end = E;
  for (int i = base + threadIdx.x; i < end; i += 256)
    atomicAdd(&h[edge_key(a_key, f_key, e_a, i) >> 9], 1);
  __syncthreads();
  for (int i = threadIdx.x; i < 512; i += 256) blkhist[i * B + blockIdx.x] = h[i];
}

// One block per bin: exclusive prefix over the bin's B block-counts (in
// place) + bin total.
__global__ __launch_bounds__(256) void cursor_kernel(int* __restrict__ blkhist, int B,
                                                     int* __restrict__ bintotal) {
  __shared__ int part[256];
  int* row = blkhist + (size_t)blockIdx.x * B;
  int C = (B + 255) / 256;
  int start = threadIdx.x * C;
  int end = start + C;
  if (end > B) end = B;
  int v[8];  // C <= 8 for B <= 2048
  int s = 0;
  for (int j = start; j < end; ++j) {
    v[j - start] = row[j];
    s += v[j - start];
  }
  part[threadIdx.x] = s;
  __syncthreads();
  for (int o = 1; o < 256; o <<= 1) {
    int u = (threadIdx.x >= o) ? part[threadIdx.x - o] : 0;
    __syncthreads();
    part[threadIdx.x] += u;
    __syncthreads();
  }
  int run = part[threadIdx.x] - s;  // exclusive
  for (int j = start; j < end; ++j) {
    row[j] = run;
    run += v[j - start];
  }
  if (threadIdx.x == 255) bintotal[blockIdx.x] = part[255];
}

// Exclusive scan of 512 bin totals -> binstart. One block of 256.
__global__ __launch_bounds__(256) void binscan_kernel(const int* __restrict__ bintotal,
                                                      int* __restrict__ binstart) {
  __shared__ int x[512];
  x[threadIdx.x] = bintotal[threadIdx.x];
  x[threadIdx.x + 256] = bintotal[threadIdx.x + 256];
  __syncthreads();
  for (int o = 1; o < 512; o <<= 1) {
    int i0 = threadIdx.x, i1 = threadIdx.x + 256;
    int v0 = (i0 >= o) ? x[i0 - o] : 0;
    int v1 = (i1 >= o) ? x[i1 - o] : 0;
    __syncthreads();
    x[i0] += v0;
    x[i1] += v1;
    __syncthreads();
  }
  binstart[threadIdx.x] = x[threadIdx.x] - bintotal[threadIdx.x];
  binstart[threadIdx.x + 256] = x[threadIdx.x + 256] - bintotal[threadIdx.x + 256];
}

// Phase-1 scatter (dst): packed output (low9<<17 | src), cursors precomputed.
__global__ __launch_bounds__(256) void scatter_dst_kernel(
    const int* __restrict__ a_key, const int* __restrict__ f_key,
    const int* __restrict__ a_pay, const int* __restrict__ f_pay,
    int e_a, int E, const int* __restrict__ blkhist, int B,
    const int* __restrict__ binstart, int* __restrict__ opack) {
  __shared__ int cur[512];
  int b = blockIdx.x;
  for (int bin = threadIdx.x; bin < 512; bin += 256)
    cur[bin] = binstart[bin] + blkhist[bin * B + b];
  __syncthreads();
  int base = b * SORT_T;
  int end = base + SORT_T;
  if (end > E) end = E;
  for (int i = base + threadIdx.x; i < end; i += 256) {
    int k = edge_key(a_key, f_key, e_a, i);
    int pay = (i < e_a) ? a_pay[i] : f_pay[i - e_a];
    int pos = atomicAdd(&cur[k >> 9], 1);
    opack[pos] = ((k & 511) << 17) | pay;
  }
}

// Phase-1 scatter (src): u16 low-key only.
__global__ __launch_bounds__(256) void scatter_src_kernel(
    const int* __restrict__ a_key, const int* __restrict__ f_key,
    int e_a, int E, const int* __restrict__ blkhist, int B,
    const int* __restrict__ binstart, unsigned short* __restrict__ okey) {
  __shared__ int cur[512];
  int b = blockIdx.x;
  for (int bin = threadIdx.x; bin < 512; bin += 256)
    cur[bin] = binstart[bin] + blkhist[bin * B + b];
  __syncthreads();
  int base = b * SORT_T;
  int end = base + SORT_T;
  if (end > E) end = E;
  for (int i = base + threadIdx.x; i < end; i += 256) {
    int k = edge_key(a_key, f_key, e_a, i);
    int pos = atomicAdd(&cur[k >> 9], 1);
    okey[pos] = (unsigned short)(k & 511);
  }
}

// Phase-2 (dst): per-bucket LDS counting sort over low 9 bits. Writes csr
// (payload) at final positions and offs for the bucket's 512 node keys.
__global__ __launch_bounds__(256) void bucket_dst_kernel(
    const int* __restrict__ kp, const int* __restrict__ binstart, int E, int e_a,
    int* __restrict__ csr, int* __restrict__ offs_a, int n_a,
    int* __restrict__ offs_f, int n_f) {
  __shared__ int h[512], x[512], cur[512];
  int b = blockIdx.x;
  int s = binstart[b];
  int e = (b == 511) ? E : binstart[b + 1];
  for (int i = threadIdx.x; i < 512; i += 256) h[i] = 0;
  __syncthreads();
  for (int i = s + threadIdx.x; i < e; i += 256) atomicAdd(&h[kp[i] >> 17], 1);
  __syncthreads();
  for (int i = threadIdx.x; i < 512; i += 256) x[i] = h[i];
  __syncthreads();
  for (int o = 1; o < 512; o <<= 1) {
    int i0 = threadIdx.x, i1 = threadIdx.x + 256;
    int v0 = (i0 >= o) ? x[i0 - o] : 0;
    int v1 = (i1 >= o) ? x[i1 - o] : 0;
    __syncthreads();
    x[i0] += v0;
    x[i1] += v1;
    __syncthreads();
  }
  for (int low = threadIdx.x; low < 512; low += 256) {
    int gpos = s + x[low] - h[low];  // exclusive start of this key's run
    cur[low] = gpos;
    int key = (b << 9) | low;
    if (key < 65536) {
      if (key < n_a) offs_a[key] = gpos;
    } else {
      int v = key - 65536;
      if (v < n_f) offs_f[v] = gpos - e_a;
    }
  }
  __syncthreads();
  for (int i = s + threadIdx.x; i < e; i += 256) {
    int pv = kp[i];
    int pos = atomicAdd(&cur[pv >> 17], 1);
    csr[pos] = pv & 0x1FFFF;
  }
}

// Phase-2 (src): histogram + scan only -> offs_src (out-degree boundaries).
__global__ __launch_bounds__(256) void bucket_src_kernel(
    const unsigned short* __restrict__ kl, const int* __restrict__ binstart, int E, int e_a,
    int* __restrict__ offs_src_a, int n_a, int* __restrict__ offs_src_f, int n_f) {
  __shared__ int h[512], x[512];
  int b = blockIdx.x;
  int s = binstart[b];
  int e = (b == 511) ? E : binstart[b + 1];
  for (int i = threadIdx.x; i < 512; i += 256) h[i] = 0;
  __syncthreads();
  for (int i = s + threadIdx.x; i < e; i += 256) atomicAdd(&h[kl[i]], 1);
  __syncthreads();
  for (int i = threadIdx.x; i < 512; i += 256) x[i] = h[i];
  __syncthreads();
  for (int o = 1; o < 512; o <<= 1) {
    int i0 = threadIdx.x, i1 = threadIdx.x + 256;
    int v0 = (i0 >= o) ? x[i0 - o] : 0;
    int v1 = (i1 >= o) ? x[i1 - o] : 0;
    __syncthreads();
    x[i0] += v0;
    x[i1] += v1;
    __syncthreads();
  }
  for (int low = threadIdx.x; low < 512; low += 256) {
    int gpos = s + x[low] - h[low];
    int key = (b << 9) | low;
    if (key < 65536) {
      if (key < n_a) offs_src_a[key] = gpos;
    } else {
      int v = key - 65536;
      if (v < n_f) offs_src_f[v] = gpos - e_a;
    }
  }
}

// isr from offs diffs (needs sentinels).
__global__ void isr_kernel(const int* __restrict__ offs_a, const int* __restrict__ offs_src_a,
                           float* __restrict__ io_a, float* __restrict__ ii_a, int n_a,
                           const int* __restrict__ offs_f, const int* __restrict__ offs_src_f,
                           float* __restrict__ io_f, float* __restrict__ ii_f, int n_f) {
  int i = blockIdx.x * blockDim.x + threadIdx.x;
  if (i < n_a) {
    int ci = offs_a[i + 1] - offs_a[i];
    int co = offs_src_a[i + 1] - offs_src_a[i];
    ii_a[i] = 1.0f / sqrtf((float)(ci < 1 ? 1 : ci));
    io_a[i] = 1.0f / sqrtf((float)(co < 1 ? 1 : co));
  }
  if (i < n_f) {
    int ci = offs_f[i + 1] - offs_f[i];
    int co = offs_src_f[i + 1] - offs_src_f[i];
    ii_f[i] = 1.0f / sqrtf((float)(ci < 1 ? 1 : ci));
    io_f[i] = 1.0f / sqrtf((float)(co < 1 ? 1 : co));
  }
}

// ---------------------------------------------------------------------------
// bf16-MFMA GEMM: C[M,N] = epi( (A[M,K](+s*add_vec[K])) @ B[K,N] )
// A fp32 or bf16 in global (in_bf16); cast/kept bf16 in LDS staging; fp32
// MFMA accumulate. epi: *rowscale[M]? +bias[N]? out bf16 or fp32.
// N%64==0, K%64==0.
// ---------------------------------------------------------------------------
#define LDT 72
__global__ __launch_bounds__(256) void gemm_mfma_kernel(
    const void* __restrict__ A, const float* __restrict__ B, void* __restrict__ C,
    int M, int N, int K,
    const float* __restrict__ add_vec, float add_scale,
    const float* __restrict__ rowscale, const float* __restrict__ bias,
    int in_bf16, int out_bf16) {
  __shared__ __align__(16) short As[64 * LDT];  // [m][k]
  __shared__ __align__(16) short Bs[64 * LDT];  // [n][k] (transposed)
  const int m0 = blockIdx.x * 64, n0 = blockIdx.y * 64;
  const int tid = threadIdx.x;
  const int lane = tid & 63, w = tid >> 6;
  const int q = lane >> 4, l16 = lane & 15;
  const int srow = tid >> 2, schunk = (tid & 3) * 16;
  f32x4 acc[4] = {};
  for (int k0 = 0; k0 < K; k0 += 64) {
    {
      int m = m0 + srow;
      float tmp[16];
      if (m < M) {
        if (in_bf16) {
          const unsigned short* s = (const unsigned short*)A + (size_t)m * K + k0 + schunk;
          u16x8 v0 = *reinterpret_cast<const u16x8*>(s);
          u16x8 v1 = *reinterpret_cast<const u16x8*>(s + 8);
#pragma unroll
          for (int i = 0; i < 8; ++i) {
            tmp[i] = bf2f(v0[i]);
            tmp[8 + i] = bf2f(v1[i]);
          }
        } else {
          const float* s = (const float*)A + (size_t)m * K + k0 + schunk;
#pragma unroll
          for (int i = 0; i < 16; i += 4) {
            float4 v = *reinterpret_cast<const float4*>(s + i);
            tmp[i] = v.x; tmp[i + 1] = v.y; tmp[i + 2] = v.z; tmp[i + 3] = v.w;
          }
        }
        if (add_vec) {
#pragma unroll
          for (int i = 0; i < 16; ++i) tmp[i] += add_scale * add_vec[k0 + schunk + i];
        }
      } else {
#pragma unroll
        for (int i = 0; i < 16; ++i) tmp[i] = 0.f;
      }
#pragma unroll
      for (int i = 0; i < 16; ++i) As[srow * LDT + schunk + i] = (short)f2bf(tmp[i]);
    }
    {
      const float* s = B + (size_t)(k0 + srow) * N + n0 + schunk;
#pragma unroll
      for (int i = 0; i < 16; i += 4) {
        float4 v = *reinterpret_cast<const float4*>(s + i);
        Bs[(schunk + i + 0) * LDT + srow] = (short)f2bf(v.x);
        Bs[(schunk + i + 1) * LDT + srow] = (short)f2bf(v.y);
        Bs[(schunk + i + 2) * LDT + srow] = (short)f2bf(v.z);
        Bs[(schunk + i + 3) * LDT + srow] = (short)f2bf(v.w);
      }
    }
    __syncthreads();
#pragma unroll
    for (int kk = 0; kk < 2; ++kk) {
      bf16x8 af = *reinterpret_cast<const bf16x8*>(&As[(w * 16 + l16) * LDT + kk * 32 + q * 8]);
#pragma unroll
      for (int nt = 0; nt < 4; ++nt) {
        bf16x8 bf = *reinterpret_cast<const bf16x8*>(&Bs[(nt * 16 + l16) * LDT + kk * 32 + q * 8]);
        acc[nt] = __builtin_amdgcn_mfma_f32_16x16x32_bf16(af, bf, acc[nt], 0, 0, 0);
      }
    }
    __syncthreads();
  }
#pragma unroll
  for (int nt = 0; nt < 4; ++nt) {
    int gcol = n0 + nt * 16 + l16;
    float bv = bias ? bias[gcol] : 0.f;
#pragma unroll
    for (int r = 0; r < 4; ++r) {
      int grow = m0 + w * 16 + q * 4 + r;
      if (grow < M) {
        float v = acc[nt][r];
        if (rowscale) v *= rowscale[grow];
        v += bv;
        if (out_bf16)
          ((unsigned short*)C)[(size_t)grow * N + gcol] = f2bf(v);
        else
          ((float*)C)[(size_t)grow * N + gcol] = v;
      }
    }
  }
}

// h[node] = relu( (sum_{e in CSR[node]} XW_bf16[src(e)]) * isr_in[node] + b )
// 32 threads per node, 8 nodes/block, 4-wide unroll (4 row loads in flight).
// mode 0: write h rows bf16 to out[node*128..].
// mode 1: per-block channel SUMS  -> out[blockIdx*128..] (fp32 partials).
// mode 2: per-block channel MAXES -> out[blockIdx*128..] (fp32, h>=0).
__global__ __launch_bounds__(256) void agg_kernel(
    const unsigned short* __restrict__ XW, const int* __restrict__ offs,
    const int* __restrict__ csr, const float* __restrict__ isr_in,
    const float* __restrict__ bias, void* __restrict__ out, int n, int mode) {
  __shared__ float red[8][128];
  int lane = threadIdx.x & 31;
  int g = threadIdx.x >> 5;
  int node = blockIdx.x * 8 + g;
  float4 o = make_float4(0.f, 0.f, 0.f, 0.f);
  if (node < n) {
    int e0 = offs[node], e1 = offs[node + 1];
    float4 a0 = make_float4(0.f, 0.f, 0.f, 0.f);
    float4 a1 = a0, a2 = a0, a3 = a0;
    int e = e0;
    for (; e + 4 <= e1; e += 4) {
      int s0 = csr[e], s1 = csr[e + 1], s2 = csr[e + 2], s3 = csr[e + 3];
      ushort4 v0 = *reinterpret_cast<const ushort4*>(&XW[(size_t)s0 * 128 + lane * 4]);
      ushort4 v1 = *reinterpret_cast<const ushort4*>(&XW[(size_t)s1 * 128 + lane * 4]);
      ushort4 v2 = *reinterpret_cast<const ushort4*>(&XW[(size_t)s2 * 128 + lane * 4]);
      ushort4 v3 = *reinterpret_cast<const ushort4*>(&XW[(size_t)s3 * 128 + lane * 4]);
      a0.x += bf2f(v0.x); a0.y += bf2f(v0.y); a0.z += bf2f(v0.z); a0.w += bf2f(v0.w);
      a1.x += bf2f(v1.x); a1.y += bf2f(v1.y); a1.z += bf2f(v1.z); a1.w += bf2f(v1.w);
      a2.x += bf2f(v2.x); a2.y += bf2f(v2.y); a2.z += bf2f(v2.z); a2.w += bf2f(v2.w);
      a3.x += bf2f(v3.x); a3.y += bf2f(v3.y); a3.z += bf2f(v3.z); a3.w += bf2f(v3.w);
    }
    for (; e < e1; ++e) {
      int s = csr[e];
      ushort4 v = *reinterpret_cast<const ushort4*>(&XW[(size_t)s * 128 + lane * 4]);
      a0.x += bf2f(v.x); a0.y += bf2f(v.y); a0.z += bf2f(v.z); a0.w += bf2f(v.w);
    }
    float4 acc;
    acc.x = (a0.x + a1.x) + (a2.x + a3.x);
    acc.y = (a0.y + a1.y) + (a2.y + a3.y);
    acc.z = (a0.z + a1.z) + (a2.z + a3.z);
    acc.w = (a0.w + a1.w) + (a2.w + a3.w);
    float sc = isr_in[node];
    float4 b = *reinterpret_cast<const float4*>(&bias[lane * 4]);
    o.x = fmaxf(fmaf(acc.x, sc, b.x), 0.f);
    o.y = fmaxf(fmaf(acc.y, sc, b.y), 0.f);
    o.z = fmaxf(fmaf(acc.z, sc, b.z), 0.f);
    o.w = fmaxf(fmaf(acc.w, sc, b.w), 0.f);
  }
  if (mode == 0) {
    if (node < n) {
      ushort4 st;
      st.x = f2bf(o.x); st.y = f2bf(o.y); st.z = f2bf(o.z); st.w = f2bf(o.w);
      *reinterpret_cast<ushort4*>(&((unsigned short*)out)[(size_t)node * 128 + lane * 4]) = st;
    }
    return;
  }
  // Reduce modes: zeros from padded nodes are identity for sum and for max
  // (h >= 0 after relu).
  red[g][lane * 4 + 0] = o.x;
  red[g][lane * 4 + 1] = o.y;
  red[g][lane * 4 + 2] = o.z;
  red[g][lane * 4 + 3] = o.w;
  __syncthreads();
  if (threadIdx.x < 128) {
    float v = red[0][threadIdx.x];
    if (mode == 1) {
#pragma unroll
      for (int j = 1; j < 8; ++j) v += red[j][threadIdx.x];
    } else {
#pragma unroll
      for (int j = 1; j < 8; ++j) v = fmaxf(v, red[j][threadIdx.x]);
    }
    ((float*)out)[(size_t)blockIdx.x * 128 + threadIdx.x] = v;
  }
}

// out[col] += column sums of X[n, ncol] (fp32 or bf16); out pre-zeroed.
__global__ __launch_bounds__(256) void colsum_kernel(const void* __restrict__ X,
                                                     float* __restrict__ out, int n, int ncol,
                                                     int xbf16) {
  __shared__ float s[256];
  int col = threadIdx.x % ncol;
  int rpb = 256 / ncol;
  int rb = threadIdx.x / ncol;
  float acc = 0.f;
  for (int r = blockIdx.x * rpb + rb; r < n; r += gridDim.x * rpb) {
    size_t idx = (size_t)r * ncol + col;
    acc += xbf16 ? bf2f(((const unsigned short*)X)[idx]) : ((const float*)X)[idx];
  }
  s[threadIdx.x] = acc;
  __syncthreads();
  if (threadIdx.x < ncol) {
    float v = 0.f;
    for (int i = 0; i < rpb; ++i) v += s[threadIdx.x + i * ncol];
    atomicAdd(&out[col], v);
  }
}

// out[col] = max over rows (X >= 0; out pre-zeroed). Bit-compare trick.
__global__ __launch_bounds__(256) void colmax_kernel(const float* __restrict__ X,
                                                     unsigned* __restrict__ out, int n, int ncol) {
  __shared__ float s[256];
  int col = threadIdx.x % ncol;
  int rpb = 256 / ncol;
  int rb = threadIdx.x / ncol;
  float acc = 0.f;
  for (int r = blockIdx.x * rpb + rb; r < n; r += gridDim.x * rpb)
    acc = fmaxf(acc, X[(size_t)r * ncol + col]);
  s[threadIdx.x] = acc;
  __syncthreads();
  if (threadIdx.x < ncol) {
    float v = s[threadIdx.x];
    for (int i = 1; i < rpb; ++i) v = fmaxf(v, s[threadIdx.x + i * ncol]);
    atomicMax(&out[col], __float_as_uint(v));
  }
}

// norm_embed(a) + norm_embed(f) then @ W_cls + b_cls. Single block of 128.
__global__ __launch_bounds__(128) void final_kernel(
    const float* __restrict__ emb_a_sum, const unsigned* __restrict__ emb_f_bits,
    const float* __restrict__ W_cls, const float* __restrict__ b_cls,
    float* __restrict__ out, float inv_n_apig, int ncls) {
  __shared__ float red[128];
  __shared__ float emb[128];
  int t = threadIdx.x;
  float a = emb_a_sum[t] * inv_n_apig;
  float f = __uint_as_float(emb_f_bits[t]);

  float vals[2] = {a, f};
  float norms[2];
#pragma unroll
  for (int which = 0; which < 2; ++which) {
    float x = vals[which];
    red[t] = x;
    __syncthreads();
    for (int o = 64; o > 0; o >>= 1) {
      if (t < o) red[t] += red[t + o];
      __syncthreads();
    }
    float mean = red[0] / 128.f;
    __syncthreads();
    float d = x - mean;
    red[t] = d * d;
    __syncthreads();
    for (int o = 64; o > 0; o >>= 1) {
      if (t < o) red[t] += red[t + o];
      __syncthreads();
    }
    float stdv = sqrtf(red[0] / 127.f);  // ddof=1
    __syncthreads();
    float z = d / stdv;
    red[t] = z;
    __syncthreads();
    for (int o = 64; o > 0; o >>= 1) {
      if (t < o) red[t] = fminf(red[t], red[t + o]);
      __syncthreads();
    }
    float zmin = red[0];
    __syncthreads();
    red[t] = z;
    __syncthreads();
    for (int o = 64; o > 0; o >>= 1) {
      if (t < o) red[t] = fmaxf(red[t], red[t + o]);
      __syncthreads();
    }
    float zmax = red[0];
    __syncthreads();
    norms[which] = (z - zmin) / (zmax - zmin);
  }

  emb[t] = norms[0] + norms[1];
  __syncthreads();
  if (t < ncls) {
    float acc = b_cls[t];
    for (int k = 0; k < 128; ++k) acc = fmaf(emb[k], W_cls[k * ncls + t], acc);
    out[t] = acc;
  }
}

extern "C" void kernel_launch(void* const* d_in, const int* in_sizes, int n_in,
                              void* d_out, int out_size, void* d_ws, size_t ws_size,
                              hipStream_t stream) {
  const float* apig_feat = (const float*)d_in[0];
  const float* fcg_feat = (const float*)d_in[1];
  const float* W_a1 = (const float*)d_in[2];
  const float* b_a1 = (const float*)d_in[3];
  const float* W_a2 = (const float*)d_in[4];
  const float* b_a2 = (const float*)d_in[5];
  const float* W_f1 = (const float*)d_in[6];
  const float* b_f1 = (const float*)d_in[7];
  const float* W_f2 = (const float*)d_in[8];
  const float* b_f2 = (const float*)d_in[9];
  const float* W1 = (const float*)d_in[10];
  const float* b1 = (const float*)d_in[11];
  const float* W2 = (const float*)d_in[12];
  const float* b2 = (const float*)d_in[13];
  // d_in[14]/d_in[15] (W_attn, b_attn): dead — softmax over length-1 axis == 1.
  const float* W_cls = (const float*)d_in[16];
  const float* b_cls = (const float*)d_in[17];
  const int* a_src = (const int*)d_in[18];
  const int* a_dst = (const int*)d_in[19];
  const int* f_src = (const int*)d_in[20];
  const int* f_dst = (const int*)d_in[21];

  const int hidden = in_sizes[3];             // 128
  const int united = in_sizes[11];            // 64
  const int ncls = in_sizes[17];              // 10
  const int apig_dim = in_sizes[2] / hidden;  // 256
  const int fcg_dim = in_sizes[6] / hidden;   // 128
  const int n_a = in_sizes[0] / apig_dim;     // 50000
  const int n_f = in_sizes[1] / fcg_dim;      // 100000
  const int e_a = in_sizes[18];               // 800000
  const int e_f = in_sizes[20];               // 1600000

  // ---- workspace carve-up (all 256B aligned) ----
  char* w = (char*)d_ws;
  auto alloc = [&](size_t bytes) -> void* {
    void* p = (void*)w;
    w += (bytes + 255) & ~(size_t)255;
    return p;
  };
  const int E_tot = e_a + e_f;
  const int B = (E_tot + SORT_T - 1) / SORT_T;
  const int nblkA = (n_a + 7) / 8, nblkF = (n_f + 7) / 8;

  float* isr_out_a = (float*)alloc((size_t)n_a * 4);
  float* isr_in_a = (float*)alloc((size_t)n_a * 4);
  float* isr_out_f = (float*)alloc((size_t)n_f * 4);
  float* isr_in_f = (float*)alloc((size_t)n_f * 4);
  int* offs_a = (int*)alloc((size_t)(n_a + 1) * 4);
  int* offs_f = (int*)alloc((size_t)(n_f + 1) * 4);
  int* offs_src_a = (int*)alloc((size_t)(n_a + 1) * 4);
  int* offs_src_f = (int*)alloc((size_t)(n_f + 1) * 4);
  int* kp = (int*)alloc((size_t)E_tot * 4);   // packed dst-sort output; u16 src reuses
  int* csr = (int*)alloc((size_t)E_tot * 4);  // final CSR (apig [0,e_a), fcg [e_a,..))
  int* blkhist = (int*)alloc((size_t)512 * B * 4);
  int* bintotal = (int*)alloc((size_t)512 * 4);
  int* binstart = (int*)alloc((size_t)512 * 4);
  unsigned short* G_a = (unsigned short*)alloc((size_t)n_a * hidden * 2);  // bf16 table
  unsigned short* H_a = (unsigned short*)alloc((size_t)n_a * hidden * 2);  // h1 / a_dec (bf16)
  unsigned short* G_f = (unsigned short*)alloc((size_t)n_f * hidden * 2);
  unsigned short* H_f = (unsigned short*)alloc((size_t)n_f * hidden * 2);
  float* P = (float*)alloc((size_t)nblkF * hidden * 4);  // conv2 block partials
  unsigned short* E_a = G_a;  // enc raw (bf16, n x 64) aliases G_a (disjoint lifetimes)
  unsigned short* E_f = G_f;
  float* a_sum = (float*)alloc((size_t)united * 4);
  float* f_sum = (float*)alloc((size_t)united * 4);
  float* emb_a = (float*)alloc((size_t)hidden * 4);
  unsigned* emb_f = (unsigned*)alloc((size_t)hidden * 4);
  int* csr_a = csr;
  int* csr_f = csr + e_a;
  unsigned short* ks = (unsigned short*)kp;  // src-sort u16 keys (after dst sort done)
  (void)ws_size;
  (void)n_in;
  (void)out_size;

  dim3 blk(256);

  // ---- init tiny accumulators + offs sentinels ----
  zero_small_kernel<<<1, 128, 0, stream>>>(a_sum, f_sum, united, emb_a, emb_f, hidden,
                                           offs_a, offs_src_a, n_a, e_a,
                                           offs_f, offs_src_f, n_f, e_f);

  // ---- CSR build: dst sort (hist -> cursor -> binscan -> scatter -> bucket) ----
  radix_hist_kernel<<<B, blk, 0, stream>>>(a_dst, f_dst, e_a, E_tot, blkhist, B);
  cursor_kernel<<<512, blk, 0, stream>>>(blkhist, B, bintotal);
  binscan_kernel<<<1, blk, 0, stream>>>(bintotal, binstart);
  scatter_dst_kernel<<<B, blk, 0, stream>>>(a_dst, f_dst, a_src, f_src, e_a, E_tot,
                                            blkhist, B, binstart, kp);
  bucket_dst_kernel<<<512, blk, 0, stream>>>(kp, binstart, E_tot, e_a,
                                             csr, offs_a, n_a, offs_f, n_f);
  // ---- src sort (keys only) -> offs_src (out-degrees) ----
  radix_hist_kernel<<<B, blk, 0, stream>>>(a_src, f_src, e_a, E_tot, blkhist, B);
  cursor_kernel<<<512, blk, 0, stream>>>(blkhist, B, bintotal);
  binscan_kernel<<<1, blk, 0, stream>>>(bintotal, binstart);
  scatter_src_kernel<<<B, blk, 0, stream>>>(a_src, f_src, e_a, E_tot, blkhist, B,
                                            binstart, ks);
  bucket_src_kernel<<<512, blk, 0, stream>>>(ks, binstart, E_tot, e_a,
                                             offs_src_a, n_a, offs_src_f, n_f);
  isr_kernel<<<(n_f + 255) / 256, blk, 0, stream>>>(offs_a, offs_src_a, isr_out_a, isr_in_a,
                                                    n_a, offs_f, offs_src_f, isr_out_f,
                                                    isr_in_f, n_f);

  const int ga = (n_a + 63) / 64, gf = (n_f + 63) / 64;

  // ---- apig conv1 + enc ----
  gemm_mfma_kernel<<<dim3(ga, hidden / 64), blk, 0, stream>>>(
      apig_feat, W_a1, G_a, n_a, hidden, apig_dim, nullptr, 0.f, isr_out_a, nullptr, 0, 1);
  agg_kernel<<<nblkA, blk, 0, stream>>>(G_a, offs_a, csr_a, isr_in_a, b_a1, H_a, n_a, 0);
  gemm_mfma_kernel<<<dim3(ga, united / 64), blk, 0, stream>>>(
      H_a, W1, E_a, n_a, united, hidden, nullptr, 0.f, nullptr, b1, 1, 1);  // E_a=G_a (dead)
  colsum_kernel<<<256, blk, 0, stream>>>(E_a, a_sum, n_a, united, 1);

  // ---- fcg conv1 + enc ----
  gemm_mfma_kernel<<<dim3(gf, hidden / 64), blk, 0, stream>>>(
      fcg_feat, W_f1, G_f, n_f, hidden, fcg_dim, nullptr, 0.f, isr_out_f, nullptr, 0, 1);
  agg_kernel<<<nblkF, blk, 0, stream>>>(G_f, offs_f, csr_f, isr_in_f, b_f1, H_f, n_f, 0);
  gemm_mfma_kernel<<<dim3(gf, united / 64), blk, 0, stream>>>(
      H_f, W1, E_f, n_f, united, hidden, nullptr, 0.f, nullptr, b1, 1, 1);
  colsum_kernel<<<256, blk, 0, stream>>>(E_f, f_sum, n_f, united, 1);

  // ---- apig dec + conv2 + mean (H2 never materialized) ----
  gemm_mfma_kernel<<<dim3(ga, hidden / 64), blk, 0, stream>>>(
      E_a, W2, H_a, n_a, hidden, united, f_sum, 0.1f, nullptr, b2, 1, 1);  // a_dec -> H_a
  gemm_mfma_kernel<<<dim3(ga, hidden / 64), blk, 0, stream>>>(
      H_a, W_a2, G_a, n_a, hidden, hidden, nullptr, 0.f, isr_out_a, nullptr, 1, 1);
  agg_kernel<<<nblkA, blk, 0, stream>>>(G_a, offs_a, csr_a, isr_in_a, b_a2, P, n_a, 1);
  colsum_kernel<<<256, blk, 0, stream>>>(P, emb_a, nblkA, hidden, 0);

  // ---- fcg dec + conv2 + max ----
  gemm_mfma_kernel<<<dim3(gf, hidden / 64), blk, 0, stream>>>(
      E_f, W2, H_f, n_f, hidden, united, a_sum, 0.1f, nullptr, b2, 1, 1);  // f_dec -> H_f
  gemm_mfma_kernel<<<dim3(gf, hidden / 64), blk, 0, stream>>>(
      H_f, W_f2, G_f, n_f, hidden, hidden, nullptr, 0.f, isr_out_f, nullptr, 1, 1);
  agg_kernel<<<nblkF, blk, 0, stream>>>(G_f, offs_f, csr_f, isr_in_f, b_f2, P, n_f, 2);
  colmax_kernel<<<256, blk, 0, stream>>>(P, emb_f, nblkF, hidden);

  // ---- head ----
  final_kernel<<<1, 128, 0, stream>>>(emb_a, emb_f, W_cls, b_cls, (float*)d_out,
                                      1.0f / (float)n_a, ncls);
}